// Round 4
// baseline (610.622 us; speedup 1.0000x reference)
//
#include <hip/hip_runtime.h>

typedef unsigned short u16;
typedef __bf16 bf16x8 __attribute__((ext_vector_type(8)));
typedef float f32x4 __attribute__((ext_vector_type(4)));
typedef unsigned short u16x8 __attribute__((ext_vector_type(8)));
typedef unsigned short u16x4 __attribute__((ext_vector_type(4)));

static constexpr size_t MD = 802816;   // 3136*256 elements

__device__ __forceinline__ u16 f2bf(float f) {
    __bf16 h = (__bf16)f;
    return __builtin_bit_cast(unsigned short, h);
}
__device__ __forceinline__ float bf2f(u16 u) {
    return __uint_as_float(((unsigned)u) << 16);
}
__device__ __forceinline__ float gelu_f(float x) {
    return 0.5f * x * (1.0f + erff(x * 0.70710678118654752f));
}

// ------------- bf16 GEMM core, 128x128 tile, 4 waves, swapped epilogue ------
// A bf16 [3136 x K] (lda), Bt bf16 [N x K] row-major. Weights are the MFMA
// A-operand so each lane's 4 acc elems are 4 consecutive C columns (u16x4 store).
__device__ __forceinline__ void gemm_core(
    const u16* __restrict__ A, int lda,
    const u16* __restrict__ Bt, int K,
    const float* __restrict__ bias,
    u16* __restrict__ C, int ldc, int act)
{
    __shared__ u16 As[128][40];
    __shared__ u16 Bs[128][40];
    const int tid  = threadIdx.x;
    const int wave = tid >> 6, lane = tid & 63;
    const int wr = wave >> 1, wc = wave & 1;
    const int l16 = lane & 15, kg = lane >> 4, kb = kg * 8;
    const int m0 = blockIdx.x * 128, n0 = blockIdx.y * 128;
    const int srow = tid >> 1, scol = (tid & 1) * 16;

    f32x4 acc[4][4];
#pragma unroll
    for (int i = 0; i < 4; i++)
#pragma unroll
        for (int j = 0; j < 4; j++) { f32x4 z = {0.f,0.f,0.f,0.f}; acc[i][j] = z; }

    const int arow = m0 + srow;
    const bool aok = arow < 3136;
    const u16* ap = A + (size_t)arow * lda + scol;
    const u16* bp = Bt + (size_t)(n0 + srow) * K + scol;
    u16x8 z8 = {0,0,0,0,0,0,0,0};
    u16x8 ua0 = aok ? *(const u16x8*)ap : z8;
    u16x8 ua1 = aok ? *(const u16x8*)(ap + 8) : z8;
    u16x8 ub0 = *(const u16x8*)bp;
    u16x8 ub1 = *(const u16x8*)(bp + 8);

    for (int kt = 0; kt < K; kt += 32) {
        *(u16x8*)&As[srow][scol]     = ua0;
        *(u16x8*)&As[srow][scol + 8] = ua1;
        *(u16x8*)&Bs[srow][scol]     = ub0;
        *(u16x8*)&Bs[srow][scol + 8] = ub1;
        __syncthreads();
        if (kt + 32 < K) {
            ua0 = aok ? *(const u16x8*)(ap + kt + 32) : z8;
            ua1 = aok ? *(const u16x8*)(ap + kt + 40) : z8;
            ub0 = *(const u16x8*)(bp + kt + 32);
            ub1 = *(const u16x8*)(bp + kt + 40);
        }
        bf16x8 af[4], bf[4];
#pragma unroll
        for (int fn = 0; fn < 4; fn++)
            af[fn] = *(const bf16x8*)&Bs[wc*64 + fn*16 + l16][kb];
#pragma unroll
        for (int fm = 0; fm < 4; fm++)
            bf[fm] = *(const bf16x8*)&As[wr*64 + fm*16 + l16][kb];
#pragma unroll
        for (int fn = 0; fn < 4; fn++)
#pragma unroll
            for (int fm = 0; fm < 4; fm++)
                acc[fn][fm] = __builtin_amdgcn_mfma_f32_16x16x32_bf16(
                    af[fn], bf[fm], acc[fn][fm], 0,0,0);
        __syncthreads();
    }
#pragma unroll
    for (int fn = 0; fn < 4; fn++) {
        int wcol = n0 + wc*64 + fn*16 + kg*4;
        f32x4 bv = *(const f32x4*)&bias[wcol];
#pragma unroll
        for (int fm = 0; fm < 4; fm++) {
            int row = m0 + wr*64 + fm*16 + l16;
            if (row < 3136) {
                u16x4 o;
#pragma unroll
                for (int r = 0; r < 4; r++) {
                    float v = acc[fn][fm][r] + bv[r];
                    if (act == 1) v = gelu_f(v);
                    o[r] = f2bf(v);
                }
                *(u16x4*)&C[(size_t)row * ldc + wcol] = o;
            }
        }
    }
}

// generic z-batched GEMM
__global__ __launch_bounds__(256) void gemm2_kernel(
    const u16* __restrict__ A, int lda, int zA,
    const u16* __restrict__ Bt, int K, int i0, int i1, int i2, int i3, int Bsz,
    const float* __restrict__ bias, int bN,
    u16* __restrict__ C, int ldc, int zC, int act)
{
    int z = blockIdx.z;
    int iz = (z == 0) ? i0 : (z == 1) ? i1 : (z == 2) ? i2 : i3;
    gemm_core(A + (size_t)z * zA, lda,
              Bt + (size_t)iz * Bsz, K,
              bias + (size_t)iz * bN,
              C + (size_t)z * zC, ldc, act);
}

// group-of-4 projections: z = inv*6 + tsr (qa,ka,va,qb,kb,vb)
__global__ __launch_bounds__(256) void proj24_kernel(
    const u16* __restrict__ s, int b0, int b1, int b2, int b3,
    int i0, int i1, int i2, int i3, const u16* __restrict__ projWt,
    const float* bqa, const float* bka, const float* bva,
    const float* bqb, const float* bkb, const float* bvb,
    u16* __restrict__ projout)
{
    int z = blockIdx.z;
    int inv = z / 6, tsr = z % 6;
    int bi = (inv == 0) ? b0 : (inv == 1) ? b1 : (inv == 2) ? b2 : b3;
    int ii = (inv == 0) ? i0 : (inv == 1) ? i1 : (inv == 2) ? i2 : i3;
    const u16* Aact = s + (size_t)((tsr < 3) ? inv : bi) * MD;
    const u16* W = projWt + (size_t)(tsr*4 + ii) * 65536;
    const float* barr[6] = {bqa, bka, bva, bqb, bkb, bvb};
    const float* bias = barr[tsr] + ii * 256;
    gemm_core(Aact, 256, W, 256, bias, projout + (size_t)z * MD, 256, 0);
}

// ---------------- flash attention core (S^T trick, b64 P stores) ------------
__device__ __forceinline__ void attn2_core(
    const u16* __restrict__ Qg, int ldq,
    const u16* __restrict__ Kg, int ldk,
    const u16* __restrict__ Vtg,          // [32 d][784 k] for this (b,h)
    u16* __restrict__ Og, int ldo,
    int qt, int rowbase, int qkcol, int ocol)
{
    __shared__ u16 Qs[64][40];
    __shared__ u16 Ks[2][64][40];
    __shared__ u16 Vts[2][48][72];        // rows 0..31 = V^T, row 32 = ones
    __shared__ u16 Ps[4][16][84];         // [wave][q][k(64) pad84]
    const int tid = threadIdx.x, wave = tid >> 6, lane = tid & 63;
    const int l16 = lane & 15, kg = lane >> 4, kb = kg * 8;
    const int sr = tid >> 2, sc8 = (tid & 3) * 8;
    const int vd = tid >> 3, vk8 = (tid & 7) * 8;

    {   // stage Q
        int qrow = qt * 64 + sr;
        u16x8 u = {0,0,0,0,0,0,0,0};
        if (qrow < 784)
            u = *(const u16x8*)(Qg + (size_t)(rowbase + qrow) * ldq + qkcol + sc8);
        *(u16x8*)&Qs[sr][sc8] = u;
    }
    // init ones/zero rows 32..47 of both V buffers (row 32 = bf16 1.0)
    for (int i = tid; i < 2*16*72; i += 256) {
        int b = (i >= 16*72);
        int rem = b ? i - 16*72 : i;
        int rr = rem / 72, cc = rem - rr*72;
        Vts[b][32 + rr][cc] = (rr == 0) ? (u16)0x3F80 : (u16)0;
    }
    u16x8 kr = {0,0,0,0,0,0,0,0}, vr = {0,0,0,0,0,0,0,0};
    {   // tile 0 direct
        kr = *(const u16x8*)(Kg + (size_t)(rowbase + sr) * ldk + qkcol + sc8);
        if (vk8 + 7 < 784) vr = *(const u16x8*)(Vtg + (size_t)vd * 784 + vk8);
        *(u16x8*)&Ks[0][sr][sc8] = kr;
        *(u16x8*)&Vts[0][vd][vk8] = vr;
    }
    __syncthreads();
    bf16x8 qfrag = *(const bf16x8*)&Qs[wave*16 + l16][kb];

    const float cexp = 0.17677669529663687f * 1.44269504088896f; // scale*log2e
    f32x4 oacc[3];
    { f32x4 z = {0.f,0.f,0.f,0.f}; oacc[0] = z; oacc[1] = z; oacc[2] = z; }

    for (int t = 0; t < 13; ++t) {
        const int cur = t & 1;
        if (t < 12) {   // prefetch next tile into regs
            u16x8 z8 = {0,0,0,0,0,0,0,0}; kr = z8; vr = z8;
            int krow = (t+1)*64 + sr;
            if (krow < 784) kr = *(const u16x8*)(Kg + (size_t)(rowbase + krow) * ldk + qkcol + sc8);
            int kc = (t+1)*64 + vk8;
            if (kc + 7 < 784) vr = *(const u16x8*)(Vtg + (size_t)vd * 784 + kc);
        }
        // S^T tile: A = K-frag (rows k), B = Q-frag (cols q)
        f32x4 sf[4];
#pragma unroll
        for (int n = 0; n < 4; n++) {
            bf16x8 kf = *(const bf16x8*)&Ks[cur][n*16 + l16][kb];
            f32x4 z = {0.f,0.f,0.f,0.f};
            sf[n] = __builtin_amdgcn_mfma_f32_16x16x32_bf16(kf, qfrag, z, 0,0,0);
        }
        // p = 2^(s*cexp); lane holds 4 consecutive k for q=l16 -> b64 store
#pragma unroll
        for (int n = 0; n < 4; n++) {
            u16x4 o;
            if (t == 12 && n > 0) { o[0]=0; o[1]=0; o[2]=0; o[3]=0; }
            else {
#pragma unroll
                for (int r = 0; r < 4; r++)
                    o[r] = f2bf(exp2f(sf[n][r] * cexp));
            }
            *(u16x4*)&Ps[wave][l16][n*16 + kg*4] = o;
        }
        // PV + ones-row (l): A = P[q][k], B = V^T[d][k]
#pragma unroll
        for (int c = 0; c < 2; c++) {
            bf16x8 pf = *(const bf16x8*)&Ps[wave][l16][c*32 + kb];
#pragma unroll
            for (int n2 = 0; n2 < 3; n2++) {
                bf16x8 vf = *(const bf16x8*)&Vts[cur][n2*16 + l16][c*32 + kb];
                oacc[n2] = __builtin_amdgcn_mfma_f32_16x16x32_bf16(pf, vf, oacc[n2], 0,0,0);
            }
        }
        if (t < 12) {
            *(u16x8*)&Ks[cur^1][sr][sc8] = kr;
            *(u16x8*)&Vts[cur^1][vd][vk8] = vr;
        }
        __syncthreads();
    }
    const int srcl = lane & 48;
    float rl[4];
#pragma unroll
    for (int r = 0; r < 4; r++) {
        float lsum = __shfl(oacc[2][r], srcl);
        rl[r] = __builtin_amdgcn_rcpf(lsum);
    }
#pragma unroll
    for (int n2 = 0; n2 < 2; n2++)
#pragma unroll
        for (int r = 0; r < 4; r++) {
            int row = qt*64 + wave*16 + kg*4 + r;
            if (row < 784)
                Og[(size_t)(rowbase + row) * ldo + ocol + n2*16 + l16] =
                    f2bf(oacc[n2][r] * rl[r]);
        }
}

// group-of-4 attention: 3328 blocks; z = inv*2 + dir, one z per XCD
__global__ __launch_bounds__(256) void attn_pair_kernel(
    const u16* __restrict__ proj, const u16* __restrict__ vt,
    u16* __restrict__ fusedin)
{
    int id = blockIdx.x;
    int wg = (id & 7) * 416 + (id >> 3);      // 3328/8 = 416
    int qt = wg % 13, bh = (wg / 13) & 31, z = wg / (13*32);
    int inv = z >> 1, dir = z & 1;
    const u16* Q  = proj + ((size_t)inv*6 + (dir ? 3 : 0)) * MD;
    const u16* K  = proj + ((size_t)inv*6 + (dir ? 1 : 4)) * MD;
    const u16* Vt = vt + (size_t)z * MD + (size_t)bh * 32 * 784;
    u16* O = fusedin + (size_t)inv * 2 * MD;
    int bb = bh >> 3, hh = bh & 7;
    attn2_core(Q, 256, K, 256, Vt, O, 512, qt, bb*784, hh*32, dir*256 + hh*32);
}

__global__ __launch_bounds__(256) void attn_mha_kernel(
    const u16* __restrict__ qkv, const u16* __restrict__ vtmha,
    u16* __restrict__ outp)
{
    int id = blockIdx.x;
    int wg = (id & 7) * 52 + (id >> 3);       // 416/8 = 52
    int qt = wg % 13, bh = wg / 13;
    int bb = bh >> 3, hh = bh & 7;
    const u16* Vt = vtmha + (size_t)bh * 32 * 784;
    attn2_core(qkv, 768, qkv + 256, 768, Vt, outp, 256, qt, bb*784, hh*32, hh*32);
}

// ---------------- LayerNorm (bf16 io): out = [prev +] os*(LN(res + tg*x)) ---
__global__ __launch_bounds__(256) void ln_kernel(
    const u16* __restrict__ x, int zx,
    const u16* __restrict__ res, int zres,
    const float* __restrict__ gamma, int i0, int i1, int i2, int i3,
    const float* __restrict__ g, const float* __restrict__ beta, int gN,
    u16* __restrict__ out, int zout,
    float outscale, int accum, int D)
{
    int z = blockIdx.y;
    int iz = (z == 0) ? i0 : (z == 1) ? i1 : (z == 2) ? i2 : i3;
    const u16* xb = x + (size_t)z * zx;
    const u16* rb = res ? res + (size_t)z * zres : (const u16*)nullptr;
    u16* ob = out + (size_t)z * zout;
    const float* gg = g + iz * gN;
    const float* bb = beta + iz * gN;
    int wave = threadIdx.x >> 6, lane = threadIdx.x & 63;
    size_t row = (size_t)blockIdx.x * 4 + wave;
    float tg = gamma ? tanhf(gamma[iz]) : 1.0f;
    const u16* xr = xb + row * D;
    const u16* rr = rb ? rb + row * D : (const u16*)nullptr;
    float vals[16];
    int nch = D >> 8;
    float s = 0.f, s2 = 0.f;
    for (int c = 0; c < nch; c++) {
        int col = c * 256 + lane * 4;
        u16x4 v = *(const u16x4*)(xr + col);
#pragma unroll
        for (int j = 0; j < 4; j++) {
            float a = tg * bf2f(v[j]);
            if (rr) a += bf2f(rr[col + j]);
            vals[c*4 + j] = a;
            s += a; s2 += a * a;
        }
    }
    for (int off = 1; off < 64; off <<= 1) {
        s  += __shfl_xor(s, off);
        s2 += __shfl_xor(s2, off);
    }
    float inv = 1.0f / D;
    float mean = s * inv;
    float var = s2 * inv - mean * mean;
    float rstd = rsqrtf(var + 1e-5f);
    for (int c = 0; c < nch; c++) {
        int col = c * 256 + lane * 4;
#pragma unroll
        for (int j = 0; j < 4; j++) {
            float o = (vals[c*4 + j] - mean) * rstd * gg[col + j] + bb[col + j];
            o *= outscale;
            if (accum) o += bf2f(ob[row*D + col + j]);
            ob[row*D + col + j] = f2bf(o);
        }
    }
}

// ---------------- layout kernels --------------------------------------------
__device__ __forceinline__ void transpose_body(const float* in, u16* out, int K, int N)
{
    __shared__ float t[32][33];
    int tx = threadIdx.x, ty = threadIdx.y;   // (32,8)
#pragma unroll
    for (int j = 0; j < 4; j++)
        t[ty + j*8][tx] = in[(size_t)(blockIdx.y*32 + ty + j*8) * N + blockIdx.x*32 + tx];
    __syncthreads();
#pragma unroll
    for (int j = 0; j < 4; j++)
        out[(size_t)(blockIdx.x*32 + ty + j*8) * K + blockIdx.y*32 + tx] =
            f2bf(t[tx][ty + j*8]);
}

__global__ __launch_bounds__(256) void transpose_w(const float* __restrict__ in,
                                                   u16* __restrict__ out, int K, int N)
{
    int z = blockIdx.z;
    transpose_body(in + (size_t)z * K * N, out + (size_t)z * K * N, K, N);
}

__global__ __launch_bounds__(256) void transpose_w6(
    const float* w0, const float* w1, const float* w2,
    const float* w3, const float* w4, const float* w5,
    u16* __restrict__ out)
{
    int z = blockIdx.z;           // 0..23: tensor = z/4, i = z%4
    const float* ws[6] = {w0,w1,w2,w3,w4,w5};
    transpose_body(ws[z >> 2] + (size_t)(z & 3) * 65536, out + (size_t)z * 65536, 256, 256);
}

// transpose V tiles into [z][bh*32+d][784]
// mode 0: proj pattern, z=0..7: off = (z/2)*6*MD + (z&1 ? 2MD : 5MD), ldin 256
// mode 1: mha: off = 512, ldin 768, z = 0
__global__ __launch_bounds__(256) void vtrans_kernel(
    const u16* __restrict__ base, int ldin, int mode,
    u16* __restrict__ outbase)
{
    __shared__ u16 t[64][40];
    int z = blockIdx.z;
    size_t off = mode ? (size_t)512
                      : ((size_t)(z >> 1) * 6 * MD + ((z & 1) ? 2*MD : 5*MD));
    const u16* in = base + off;
    u16* out = outbase + (size_t)z * MD;
    int kt = blockIdx.x, bh = blockIdx.y;
    int bb = bh >> 3, hh = bh & 7;
    int tid = threadIdx.x;
    {
        int r = tid >> 2, c8 = (tid & 3) * 8;
        int krow = kt*64 + r;
        u16x8 u = {0,0,0,0,0,0,0,0};
        if (krow < 784)
            u = *(const u16x8*)(in + (size_t)(bb*784 + krow) * ldin + hh*32 + c8);
        *(u16x8*)&t[r][c8] = u;
    }
    __syncthreads();
    int d = tid >> 3, k8 = (tid & 7) * 8;
    if (kt*64 + k8 + 7 < 784) {
        u16x8 u;
#pragma unroll
        for (int j = 0; j < 8; j++) u[j] = t[k8 + j][d];
        *(u16x8*)&out[(size_t)(bh*32 + d) * 784 + kt*64 + k8] = u;
    }
}

// f[B,256,28,28] fp32 -> s[fi][b*784+hw][d] bf16
__global__ __launch_bounds__(256) void to_seq_kernel(
    const float* f0, const float* f1, const float* f2, const float* f3,
    u16* __restrict__ sbase)
{
    __shared__ float t[16][17];
    int z = blockIdx.z;
    int fi = z & 3, b = z >> 2;
    const float* fs[4] = {f0,f1,f2,f3};
    const float* f = fs[fi] + (size_t)b * 256 * 784;
    u16* s = sbase + (size_t)fi * MD + (size_t)b * 784 * 256;
    int tx = threadIdx.x, ty = threadIdx.y;  // (16,16)
    t[ty][tx] = f[(size_t)(blockIdx.y*16 + ty) * 784 + blockIdx.x*16 + tx];
    __syncthreads();
    s[(size_t)(blockIdx.x*16 + ty) * 256 + blockIdx.y*16 + tx] = f2bf(t[tx][ty]);
}

// y[b*784+hw][d] bf16 -> out[b][d][h][w] fp32
__global__ __launch_bounds__(256) void from_seq_kernel(const u16* __restrict__ y,
                                                       float* __restrict__ out)
{
    __shared__ float t[16][17];
    int b = blockIdx.z;
    const u16* yb = y + (size_t)b * 784 * 256;
    float* ob = out + (size_t)b * 256 * 784;
    int tx = threadIdx.x, ty = threadIdx.y;
    t[ty][tx] = bf2f(yb[(size_t)(blockIdx.x*16 + ty) * 256 + blockIdx.y*16 + tx]);
    __syncthreads();
    ob[(size_t)(blockIdx.y*16 + ty) * 784 + blockIdx.x*16 + tx] = t[tx][ty];
}

// ---------------- host orchestration ----------------------------------------
extern "C" void kernel_launch(void* const* d_in, const int* in_sizes, int n_in,
                              void* d_out, int out_size, void* d_ws, size_t ws_size,
                              hipStream_t stream)
{
    (void)in_sizes; (void)n_in; (void)out_size; (void)ws_size;
    const float* f0 = (const float*)d_in[0];
    const float* f1 = (const float*)d_in[1];
    const float* f2 = (const float*)d_in[2];
    const float* f3 = (const float*)d_in[3];
    const float* Wq_a = (const float*)d_in[4];
    const float* Wk_a = (const float*)d_in[5];
    const float* Wv_a = (const float*)d_in[6];
    const float* Wq_b = (const float*)d_in[7];
    const float* Wk_b = (const float*)d_in[8];
    const float* Wv_b = (const float*)d_in[9];
    const float* bq_a = (const float*)d_in[10];
    const float* bk_a = (const float*)d_in[11];
    const float* bv_a = (const float*)d_in[12];
    const float* bq_b = (const float*)d_in[13];
    const float* bk_b = (const float*)d_in[14];
    const float* bv_b = (const float*)d_in[15];
    const float* gamma = (const float*)d_in[16];
    const float* gamma_ffn = (const float*)d_in[17];
    const float* Wfuse = (const float*)d_in[18];
    const float* bfuse = (const float*)d_in[19];
    const float* W1 = (const float*)d_in[20];
    const float* b1 = (const float*)d_in[21];
    const float* W2 = (const float*)d_in[22];
    const float* b2 = (const float*)d_in[23];
    const float* ln1_g = (const float*)d_in[24];
    const float* ln1_b = (const float*)d_in[25];
    const float* ln2_g = (const float*)d_in[26];
    const float* ln2_b = (const float*)d_in[27];
    const float* fp_ln_g = (const float*)d_in[28];
    const float* fp_ln_b = (const float*)d_in[29];
    const float* fp_W = (const float*)d_in[30];
    const float* fp_b = (const float*)d_in[31];
    const float* ff_ln_g = (const float*)d_in[32];
    const float* ff_ln_b = (const float*)d_in[33];
    const float* ff_W = (const float*)d_in[34];
    const float* ff_b = (const float*)d_in[35];
    const float* mha_Wqkv = (const float*)d_in[36];
    const float* mha_bqkv = (const float*)d_in[37];
    const float* mha_Wo = (const float*)d_in[38];
    const float* mha_bo = (const float*)d_in[39];
    const float* norm_g = (const float*)d_in[40];
    const float* norm_b = (const float*)d_in[41];

    u16* W = (u16*)d_ws;
    u16* projWt = W;                          // 1572864
    u16* fuseWt = projWt + 1572864;           // 524288
    u16* W1t    = fuseWt + 524288;            // 1048576
    u16* W2t    = W1t + 1048576;              // 1048576
    u16* fpWt   = W2t + 1048576;              // 65536
    u16* ffWt   = fpWt + 65536;               // 262144
    u16* qkvWt  = ffWt + 262144;              // 196608
    u16* WoWt   = qkvWt + 196608;             // 65536
    u16* act    = WoWt + 65536;

    u16* s    = act;               // 4 MD
    u16* e    = act + 4*MD;        // 4 MD
    u16* proj = act + 8*MD;        // 24 MD
    u16* vt   = act + 32*MD;       // 8 MD
    u16* fin  = act + 40*MD;       // 8 MD   (peak: 48 MD)
    // overlays (proj dead after attn; vt dead after attn)
    u16* ffh  = proj;              // 16 MD
    u16* fb   = proj + 16*MD;      // 4 MD
    u16* xa1  = proj + 20*MD;      // 4 MD
    u16* ffb  = vt;                // 4 MD

    // input layout + weight pre-transpose
    to_seq_kernel<<<dim3(49,16,16), dim3(16,16), 0, stream>>>(f0,f1,f2,f3, s);
    transpose_w6<<<dim3(8,8,24), dim3(32,8), 0, stream>>>(Wq_a,Wk_a,Wv_a,Wq_b,Wk_b,Wv_b, projWt);
    transpose_w<<<dim3(8,16,4), dim3(32,8), 0, stream>>>(Wfuse, fuseWt, 512, 256);
    transpose_w<<<dim3(32,8,4), dim3(32,8), 0, stream>>>(W1, W1t, 256, 1024);
    transpose_w<<<dim3(8,32,4), dim3(32,8), 0, stream>>>(W2, W2t, 1024, 256);
    transpose_w<<<dim3(8,8,1),  dim3(32,8), 0, stream>>>(fp_W, fpWt, 256, 256);
    transpose_w<<<dim3(8,32,1), dim3(32,8), 0, stream>>>(ff_W, ffWt, 1024, 256);
    transpose_w<<<dim3(24,8,1), dim3(32,8), 0, stream>>>(mha_Wqkv, qkvWt, 256, 768);
    transpose_w<<<dim3(8,8,1),  dim3(32,8), 0, stream>>>(mha_Wo, WoWt, 256, 256);

    // two groups of 4 independent block invocations (distinct e-targets):
    // A = {bi0,bi2,bi4,bi6}: i={0,0,2,1}, b={1,0,1,0}, accum=0
    // B = {bi1,bi3,bi5,bi7}: i={1,2,3,3}, b={3,2,3,2}, accum=1
    const int GI[2][4] = {{0,0,2,1},{1,2,3,3}};
    const int GB[2][4] = {{1,0,1,0},{3,2,3,2}};

    for (int g = 0; g < 2; g++) {
        int i0 = GI[g][0], i1 = GI[g][1], i2 = GI[g][2], i3 = GI[g][3];
        proj24_kernel<<<dim3(25,2,24), 256, 0, stream>>>(s,
            GB[g][0], GB[g][1], GB[g][2], GB[g][3], i0, i1, i2, i3,
            projWt, bq_a, bk_a, bv_a, bq_b, bk_b, bv_b, proj);
        vtrans_kernel<<<dim3(13,32,8), 256, 0, stream>>>(proj, 256, 0, vt);
        attn_pair_kernel<<<3328, 256, 0, stream>>>(proj, vt, fin);
        gemm2_kernel<<<dim3(25,2,4), 256, 0, stream>>>(fin, 512, (int)(2*MD),
            fuseWt, 512, i0, i1, i2, i3, 131072, bfuse, 256, fb, 256, (int)MD, 0);
        ln_kernel<<<dim3(784,4), 256, 0, stream>>>(fb, (int)MD,
            s, (int)MD, gamma, i0, i1, i2, i3, ln1_g, ln1_b, 256,
            xa1, (int)MD, 1.0f, 0, 256);
        gemm2_kernel<<<dim3(25,8,4), 256, 0, stream>>>(xa1, 256, (int)MD,
            W1t, 256, i0, i1, i2, i3, 262144, b1, 1024, ffh, 1024, (int)(4*MD), 1);
        gemm2_kernel<<<dim3(25,2,4), 256, 0, stream>>>(ffh, 1024, (int)(4*MD),
            W2t, 1024, i0, i1, i2, i3, 262144, b2, 256, ffb, 256, (int)MD, 0);
        ln_kernel<<<dim3(784,4), 256, 0, stream>>>(ffb, (int)MD,
            xa1, (int)MD, gamma_ffn, i0, i1, i2, i3, ln2_g, ln2_b, 256,
            e, (int)MD, 0.5f, g, 256);
    }

    // final fuse stage (reuse dead scratch; e is live until ln4 done)
    u16* ln4    = act + 8*MD;        // 4 MD
    u16* allf   = act + 12*MD;       // 4 MD  [3136][1024]
    u16* ffln   = act + 16*MD;       // 4 MD
    u16* x2     = act + 20*MD;       // 1 MD
    u16* qkv    = act + 21*MD;       // 3 MD  [3136][768]
    u16* vtmha  = act + 24*MD;       // 1 MD
    u16* attn_o = act + 25*MD;       // 1 MD
    u16* ymid   = act + 26*MD;       // 1 MD
    u16* yfin   = act + 27*MD;       // 1 MD

    ln_kernel<<<dim3(784,4), 256, 0, stream>>>(e, (int)MD,
        (const u16*)nullptr, 0, (const float*)nullptr, 0,0,0,0,
        fp_ln_g, fp_ln_b, 0, ln4, (int)MD, 1.0f, 0, 256);
    gemm2_kernel<<<dim3(25,2,4), 256, 0, stream>>>(ln4, 256, (int)MD,
        fpWt, 256, 0,0,0,0, 0, fp_b, 0, allf, 1024, 256, 1);
    ln_kernel<<<dim3(784,1), 256, 0, stream>>>(allf, 0,
        (const u16*)nullptr, 0, (const float*)nullptr, 0,0,0,0,
        ff_ln_g, ff_ln_b, 0, ffln, 0, 1.0f, 0, 1024);
    gemm2_kernel<<<dim3(25,2,1), 256, 0, stream>>>(ffln, 1024, 0,
        ffWt, 1024, 0,0,0,0, 0, ff_b, 0, x2, 256, 0, 1);
    gemm2_kernel<<<dim3(25,6,1), 256, 0, stream>>>(x2, 256, 0,
        qkvWt, 256, 0,0,0,0, 0, mha_bqkv, 0, qkv, 768, 0, 0);
    vtrans_kernel<<<dim3(13,32,1), 256, 0, stream>>>(qkv, 768, 1, vtmha);
    attn_mha_kernel<<<416, 256, 0, stream>>>(qkv, vtmha, attn_o);
    gemm2_kernel<<<dim3(25,2,1), 256, 0, stream>>>(attn_o, 256, 0,
        WoWt, 256, 0,0,0,0, 0, mha_bo, 0, ymid, 256, 0, 0);
    ln_kernel<<<dim3(784,1), 256, 0, stream>>>(ymid, 0,
        (const u16*)nullptr, 0, (const float*)nullptr, 0,0,0,0,
        norm_g, norm_b, 0, yfin, 0, 1.0f, 0, 256);
    from_seq_kernel<<<dim3(49,16,4), dim3(16,16), 0, stream>>>(yfin, (float*)d_out);
}

// Round 5
// 513.891 us; speedup vs baseline: 1.1882x; 1.1882x over previous
//
#include <hip/hip_runtime.h>

typedef unsigned short u16;
typedef __bf16 bf16x8 __attribute__((ext_vector_type(8)));
typedef float f32x4 __attribute__((ext_vector_type(4)));
typedef unsigned short u16x8 __attribute__((ext_vector_type(8)));
typedef unsigned short u16x4 __attribute__((ext_vector_type(4)));

static constexpr size_t MD = 802816;   // 3136*256 elements

__device__ __forceinline__ u16 f2bf(float f) {
    __bf16 h = (__bf16)f;
    return __builtin_bit_cast(unsigned short, h);
}
__device__ __forceinline__ float bf2f(u16 u) {
    return __uint_as_float(((unsigned)u) << 16);
}
__device__ __forceinline__ float gelu_f(float x) {
    return 0.5f * x * (1.0f + erff(x * 0.70710678118654752f));
}
// pack two f32 -> two bf16 in one u32 (low = a, high = b)
__device__ __forceinline__ unsigned cvt_pk_bf16(float a, float b) {
    unsigned r;
    asm("v_cvt_pk_bf16_f32 %0, %1, %2" : "=v"(r) : "v"(a), "v"(b));
    return r;
}

// ------------- bf16 GEMM core, 64x64 tile, 4 waves, swapped epilogue --------
// A bf16 [3136 x K] (lda), Bt bf16 [N x K] row-major. Weights are the MFMA
// first operand so each lane's 4 acc elems are 4 consecutive C columns.
__device__ __forceinline__ void gemm_core(
    const u16* __restrict__ A, int lda,
    const u16* __restrict__ Bt, int K,
    const float* __restrict__ bias,
    u16* __restrict__ C, int ldc, int act)
{
    __shared__ u16 As[64][40];
    __shared__ u16 Bs[64][40];
    const int tid  = threadIdx.x;
    const int wave = tid >> 6, lane = tid & 63;
    const int wr = wave >> 1, wc = wave & 1;
    const int l16 = lane & 15, kg = lane >> 4, kb = kg * 8;
    const int m0 = blockIdx.x * 64, n0 = blockIdx.y * 64;
    const int srow = tid >> 2, scol = (tid & 3) * 8;

    f32x4 acc[2][2];   // [n-frag][m-frag]
#pragma unroll
    for (int j = 0; j < 2; j++)
#pragma unroll
        for (int i = 0; i < 2; i++) { f32x4 z = {0.f,0.f,0.f,0.f}; acc[j][i] = z; }

    const u16* ap = A + (size_t)(m0 + srow) * lda + scol;
    const u16* bp = Bt + (size_t)(n0 + srow) * K + scol;
    u16x8 ua = *(const u16x8*)ap;
    u16x8 ub = *(const u16x8*)bp;

    for (int kt = 0; kt < K; kt += 32) {
        *(u16x8*)&As[srow][scol] = ua;
        *(u16x8*)&Bs[srow][scol] = ub;
        __syncthreads();
        if (kt + 32 < K) {
            ua = *(const u16x8*)(ap + kt + 32);
            ub = *(const u16x8*)(bp + kt + 32);
        }
        bf16x8 af[2], bf[2];
#pragma unroll
        for (int j = 0; j < 2; j++)
            af[j] = *(const bf16x8*)&Bs[wc*32 + j*16 + l16][kb];
#pragma unroll
        for (int i = 0; i < 2; i++)
            bf[i] = *(const bf16x8*)&As[wr*32 + i*16 + l16][kb];
#pragma unroll
        for (int j = 0; j < 2; j++)
#pragma unroll
            for (int i = 0; i < 2; i++)
                acc[j][i] = __builtin_amdgcn_mfma_f32_16x16x32_bf16(
                    af[j], bf[i], acc[j][i], 0,0,0);
        __syncthreads();
    }
#pragma unroll
    for (int j = 0; j < 2; j++) {
        int wcol = n0 + wc*32 + j*16 + kg*4;
        f32x4 bv = *(const f32x4*)&bias[wcol];
#pragma unroll
        for (int i = 0; i < 2; i++) {
            int row = m0 + wr*32 + i*16 + l16;
            u16x4 o;
#pragma unroll
            for (int r = 0; r < 4; r++) {
                float v = acc[j][i][r] + bv[r];
                if (act == 1) v = gelu_f(v);
                o[r] = f2bf(v);
            }
            *(u16x4*)&C[(size_t)row * ldc + wcol] = o;
        }
    }
}

// generic z-batched GEMM
__global__ __launch_bounds__(256) void gemm2_kernel(
    const u16* __restrict__ A, int lda, int zA,
    const u16* __restrict__ Bt, int K, int i0, int i1, int i2, int i3, int Bsz,
    const float* __restrict__ bias, int bN,
    u16* __restrict__ C, int ldc, int zC, int act)
{
    int z = blockIdx.z;
    int iz = (z == 0) ? i0 : (z == 1) ? i1 : (z == 2) ? i2 : i3;
    gemm_core(A + (size_t)z * zA, lda,
              Bt + (size_t)iz * Bsz, K,
              bias + (size_t)iz * bN,
              C + (size_t)z * zC, ldc, act);
}

// cat projections: z = inv*2 + ab; output [3136][768] (q|k|v) per (inv,ab)
__global__ __launch_bounds__(256) void proj8_kernel(
    const u16* __restrict__ s, int b0, int b1, int b2, int b3,
    int i0, int i1, int i2, int i3,
    const u16* __restrict__ projWt, const float* __restrict__ biasc,
    u16* __restrict__ projc)
{
    int z = blockIdx.z;
    int inv = z >> 1, ab = z & 1;
    int bi = (inv == 0) ? b0 : (inv == 1) ? b1 : (inv == 2) ? b2 : b3;
    int ii = (inv == 0) ? i0 : (inv == 1) ? i1 : (inv == 2) ? i2 : i3;
    const u16* A = s + (size_t)(ab ? bi : inv) * MD;
    int widx = ii * 2 + ab;
    gemm_core(A, 256, projWt + (size_t)widx * 768 * 256, 256,
              biasc + widx * 768,
              projc + (size_t)z * 3 * MD, 768, 0);
}

// biascat[(i*2+ab)*768 + (tsr%3)*256 + c] = barr[tsr][i*256+c];  z: tsr=z>>2,i=z&3
__global__ __launch_bounds__(256) void pack_bias_kernel(
    const float* b0, const float* b1, const float* b2,
    const float* b3, const float* b4, const float* b5,
    float* __restrict__ biasc)
{
    int z = blockIdx.x;
    int tsr = z >> 2, i = z & 3;
    const float* barr[6] = {b0,b1,b2,b3,b4,b5};
    int ab = (tsr >= 3) ? 1 : 0;
    biasc[(i*2 + ab)*768 + (tsr % 3)*256 + threadIdx.x] = barr[tsr][i*256 + threadIdx.x];
}

// ---------------- flash attention core (bf16, Vt pre-transposed) ------------
// Q pre-scaled by scale*log2e at staging; p = exp2(s). l via ones-row MFMA.
__device__ __forceinline__ void attn2_core(
    const u16* __restrict__ Qg, int ldq,
    const u16* __restrict__ Kg, int ldk,
    const u16* __restrict__ Vtg,          // [32 d][784 k] for this (b,h)
    u16* __restrict__ Og, int ldo,
    int qt, int rowbase, int qkcol, int ocol)
{
    __shared__ u16 Qs[64][40];
    __shared__ u16 Ks[2][64][40];
    __shared__ u16 Vts[2][48][72];        // rows 0..31 = V^T, row 32 = ones
    __shared__ u16 Ps[4][16][84];         // [wave][q][k(64) pad84]
    const int tid = threadIdx.x, wave = tid >> 6, lane = tid & 63;
    const int l16 = lane & 15, kg = lane >> 4, kb = kg * 8;
    const int sr = tid >> 2, sc8 = (tid & 3) * 8;
    const int vd = tid >> 3, vk8 = (tid & 7) * 8;
    const float QSC = 0.25503489f;        // 32^-0.5 * log2(e)

    {   // stage Q, pre-scaled
        int qrow = qt * 64 + sr;
        u16x8 u = {0,0,0,0,0,0,0,0};
        if (qrow < 784)
            u = *(const u16x8*)(Qg + (size_t)(rowbase + qrow) * ldq + qkcol + sc8);
#pragma unroll
        for (int j = 0; j < 8; j++) u[j] = f2bf(bf2f(u[j]) * QSC);
        *(u16x8*)&Qs[sr][sc8] = u;
    }
    // init ones/zero rows 32..47 of both V buffers (row 32 = bf16 1.0)
    for (int i = tid; i < 2*16*72; i += 256) {
        int b = (i >= 16*72);
        int rem = b ? i - 16*72 : i;
        int rr = rem / 72, cc = rem - rr*72;
        Vts[b][32 + rr][cc] = (rr == 0) ? (u16)0x3F80 : (u16)0;
    }
    u16x8 kr = {0,0,0,0,0,0,0,0}, vr = {0,0,0,0,0,0,0,0};
    {   // tile 0 direct
        kr = *(const u16x8*)(Kg + (size_t)(rowbase + sr) * ldk + qkcol + sc8);
        if (vk8 + 7 < 784) vr = *(const u16x8*)(Vtg + (size_t)vd * 784 + vk8);
        *(u16x8*)&Ks[0][sr][sc8] = kr;
        *(u16x8*)&Vts[0][vd][vk8] = vr;
    }
    __syncthreads();
    bf16x8 qfrag = *(const bf16x8*)&Qs[wave*16 + l16][kb];

    f32x4 oacc[3];
    { f32x4 z = {0.f,0.f,0.f,0.f}; oacc[0] = z; oacc[1] = z; oacc[2] = z; }

    for (int t = 0; t < 13; ++t) {
        const int cur = t & 1;
        if (t < 12) {   // prefetch next tile into regs
            u16x8 z8 = {0,0,0,0,0,0,0,0}; kr = z8; vr = z8;
            int krow = (t+1)*64 + sr;
            if (krow < 784) kr = *(const u16x8*)(Kg + (size_t)(rowbase + krow) * ldk + qkcol + sc8);
            int kc = (t+1)*64 + vk8;
            if (kc + 7 < 784) vr = *(const u16x8*)(Vtg + (size_t)vd * 784 + kc);
        }
        // S^T tile: first operand K-frag (rows k), second Q-frag (cols q)
        f32x4 sf[4];
#pragma unroll
        for (int n = 0; n < 4; n++) {
            bf16x8 kf = *(const bf16x8*)&Ks[cur][n*16 + l16][kb];
            f32x4 z = {0.f,0.f,0.f,0.f};
            sf[n] = __builtin_amdgcn_mfma_f32_16x16x32_bf16(kf, qfrag, z, 0,0,0);
        }
        // p = 2^s; lane holds 4 consecutive k for q=l16 -> b64 store
#pragma unroll
        for (int n = 0; n < 4; n++) {
            union { unsigned u[2]; u16x4 v; } pk;
            if (t == 12 && n > 0) { pk.u[0] = 0; pk.u[1] = 0; }
            else {
                float p0 = exp2f(sf[n][0]);
                float p1 = exp2f(sf[n][1]);
                float p2 = exp2f(sf[n][2]);
                float p3 = exp2f(sf[n][3]);
                pk.u[0] = cvt_pk_bf16(p0, p1);
                pk.u[1] = cvt_pk_bf16(p2, p3);
            }
            *(u16x4*)&Ps[wave][l16][n*16 + kg*4] = pk.v;
        }
        // PV + ones-row (l): first operand P[q][k], second V^T[d][k]
#pragma unroll
        for (int c = 0; c < 2; c++) {
            bf16x8 pf = *(const bf16x8*)&Ps[wave][l16][c*32 + kb];
#pragma unroll
            for (int n2 = 0; n2 < 3; n2++) {
                bf16x8 vf = *(const bf16x8*)&Vts[cur][n2*16 + l16][c*32 + kb];
                oacc[n2] = __builtin_amdgcn_mfma_f32_16x16x32_bf16(pf, vf, oacc[n2], 0,0,0);
            }
        }
        if (t < 12) {
            *(u16x8*)&Ks[cur^1][sr][sc8] = kr;
            *(u16x8*)&Vts[cur^1][vd][vk8] = vr;
        }
        __syncthreads();
    }
    const int srcl = lane & 48;
    float rl[4];
#pragma unroll
    for (int r = 0; r < 4; r++) {
        float lsum = __shfl(oacc[2][r], srcl);
        rl[r] = __builtin_amdgcn_rcpf(lsum);
    }
#pragma unroll
    for (int n2 = 0; n2 < 2; n2++)
#pragma unroll
        for (int r = 0; r < 4; r++) {
            int row = qt*64 + wave*16 + kg*4 + r;
            if (row < 784)
                Og[(size_t)(rowbase + row) * ldo + ocol + n2*16 + l16] =
                    f2bf(oacc[n2][r] * rl[r]);
        }
}

// group-of-4 attention: 3328 blocks; z = inv*2 + dir (Q side = dir, K/V = dir^1)
__global__ __launch_bounds__(256) void attn_pair_kernel(
    const u16* __restrict__ projc, const u16* __restrict__ vt,
    u16* __restrict__ fusedin)
{
    int id = blockIdx.x;
    int wg = (id & 7) * 416 + (id >> 3);      // 3328/8 = 416
    int qt = wg % 13, bh = (wg / 13) & 31, z = wg / (13*32);
    int inv = z >> 1, dir = z & 1;
    const u16* Q  = projc + (size_t)z * 3 * MD;
    const u16* K  = projc + (size_t)(z ^ 1) * 3 * MD + 256;
    const u16* Vt = vt + (size_t)z * MD + (size_t)bh * 32 * 784;
    u16* O = fusedin + (size_t)inv * 2 * MD;
    int bb = bh >> 3, hh = bh & 7;
    attn2_core(Q, 768, K, 768, Vt, O, 512, qt, bb*784, hh*32, dir*256 + hh*32);
}

__global__ __launch_bounds__(256) void attn_mha_kernel(
    const u16* __restrict__ qkv, const u16* __restrict__ vtmha,
    u16* __restrict__ outp)
{
    int id = blockIdx.x;
    int wg = (id & 7) * 52 + (id >> 3);       // 416/8 = 52
    int qt = wg % 13, bh = wg / 13;
    int bb = bh >> 3, hh = bh & 7;
    const u16* Vt = vtmha + (size_t)bh * 32 * 784;
    attn2_core(qkv, 768, qkv + 256, 768, Vt, outp, 256, qt, bb*784, hh*32, hh*32);
}

// ---------------- LayerNorm (bf16 io): out = [prev +] os*(LN(res + tg*x)) ---
__global__ __launch_bounds__(256) void ln_kernel(
    const u16* __restrict__ x, int zx,
    const u16* __restrict__ res, int zres,
    const float* __restrict__ gamma, int i0, int i1, int i2, int i3,
    const float* __restrict__ g, const float* __restrict__ beta, int gN,
    u16* __restrict__ out, int zout,
    float outscale, int accum, int D)
{
    int z = blockIdx.y;
    int iz = (z == 0) ? i0 : (z == 1) ? i1 : (z == 2) ? i2 : i3;
    const u16* xb = x + (size_t)z * zx;
    const u16* rb = res ? res + (size_t)z * zres : (const u16*)nullptr;
    u16* ob = out + (size_t)z * zout;
    const float* gg = g + iz * gN;
    const float* bb = beta + iz * gN;
    int wave = threadIdx.x >> 6, lane = threadIdx.x & 63;
    size_t row = (size_t)blockIdx.x * 4 + wave;
    float tg = gamma ? tanhf(gamma[iz]) : 1.0f;
    const u16* xr = xb + row * D;
    const u16* rr = rb ? rb + row * D : (const u16*)nullptr;
    float vals[16];
    int nch = D >> 8;
    float s = 0.f, s2 = 0.f;
    for (int c = 0; c < nch; c++) {
        int col = c * 256 + lane * 4;
        u16x4 v = *(const u16x4*)(xr + col);
#pragma unroll
        for (int j = 0; j < 4; j++) {
            float a = tg * bf2f(v[j]);
            if (rr) a += bf2f(rr[col + j]);
            vals[c*4 + j] = a;
            s += a; s2 += a * a;
        }
    }
    for (int off = 1; off < 64; off <<= 1) {
        s  += __shfl_xor(s, off);
        s2 += __shfl_xor(s2, off);
    }
    float inv = 1.0f / D;
    float mean = s * inv;
    float var = s2 * inv - mean * mean;
    float rstd = rsqrtf(var + 1e-5f);
    for (int c = 0; c < nch; c++) {
        int col = c * 256 + lane * 4;
#pragma unroll
        for (int j = 0; j < 4; j++) {
            float o = (vals[c*4 + j] - mean) * rstd * gg[col + j] + bb[col + j];
            o *= outscale;
            if (accum) o += bf2f(ob[row*D + col + j]);
            ob[row*D + col + j] = f2bf(o);
        }
    }
}

// ---------------- layout kernels --------------------------------------------
__device__ __forceinline__ void transpose_body(const float* in, u16* out, int K, int N)
{
    __shared__ float t[32][33];
    int tx = threadIdx.x, ty = threadIdx.y;   // (32,8)
#pragma unroll
    for (int j = 0; j < 4; j++)
        t[ty + j*8][tx] = in[(size_t)(blockIdx.y*32 + ty + j*8) * N + blockIdx.x*32 + tx];
    __syncthreads();
#pragma unroll
    for (int j = 0; j < 4; j++)
        out[(size_t)(blockIdx.x*32 + ty + j*8) * K + blockIdx.y*32 + tx] =
            f2bf(t[tx][ty + j*8]);
}

__global__ __launch_bounds__(256) void transpose_w(const float* __restrict__ in,
                                                   u16* __restrict__ out, int K, int N)
{
    int z = blockIdx.z;
    transpose_body(in + (size_t)z * K * N, out + (size_t)z * K * N, K, N);
}

// proj weights into cat layout: [i][ab][768 n][256 k]
__global__ __launch_bounds__(256) void transpose_w6(
    const float* w0, const float* w1, const float* w2,
    const float* w3, const float* w4, const float* w5,
    u16* __restrict__ out)
{
    int z = blockIdx.z;           // 0..23: tsr = z/4, i = z%4
    int tsr = z >> 2, i = z & 3;
    const float* ws[6] = {w0,w1,w2,w3,w4,w5};
    int ab = (tsr >= 3) ? 1 : 0;
    u16* ob = out + (size_t)((i*2 + ab)*3 + (tsr % 3)) * 65536;
    transpose_body(ws[tsr] + (size_t)i * 65536, ob, 256, 256);
}

// transpose V (cols 512..767 of a 768-wide qkv buffer) -> [z][bh*32+d][784]
// mode 0: in = base + (z^1)*3MD + 512;  mode 1: in = base + 512 (z=0)
__global__ __launch_bounds__(256) void vtrans_kernel(
    const u16* __restrict__ base, int mode,
    u16* __restrict__ outbase)
{
    __shared__ u16 t[64][44];
    int z = blockIdx.z;
    size_t off = (mode ? (size_t)0 : (size_t)(z ^ 1) * 3 * MD) + 512;
    const u16* in = base + off;
    u16* out = outbase + (size_t)z * MD;
    int kt = blockIdx.x, bh = blockIdx.y;
    int bb = bh >> 3, hh = bh & 7;
    int tid = threadIdx.x;
    {
        int r = tid >> 2, c8 = (tid & 3) * 8;
        int krow = kt*64 + r;
        u16x8 u = {0,0,0,0,0,0,0,0};
        if (krow < 784)
            u = *(const u16x8*)(in + (size_t)(bb*784 + krow) * 768 + hh*32 + c8);
        *(u16x8*)&t[r][c8] = u;
    }
    __syncthreads();
    int d = tid >> 3, k8 = (tid & 7) * 8;
    if (kt*64 + k8 + 7 < 784) {
        u16x8 u;
#pragma unroll
        for (int j = 0; j < 8; j++) u[j] = t[k8 + j][d];
        *(u16x8*)&out[(size_t)(bh*32 + d) * 784 + kt*64 + k8] = u;
    }
}

// f[B,256,28,28] fp32 -> s[fi][b*784+hw][d] bf16
__global__ __launch_bounds__(256) void to_seq_kernel(
    const float* f0, const float* f1, const float* f2, const float* f3,
    u16* __restrict__ sbase)
{
    __shared__ float t[16][17];
    int z = blockIdx.z;
    int fi = z & 3, b = z >> 2;
    const float* fs[4] = {f0,f1,f2,f3};
    const float* f = fs[fi] + (size_t)b * 256 * 784;
    u16* s = sbase + (size_t)fi * MD + (size_t)b * 784 * 256;
    int tx = threadIdx.x, ty = threadIdx.y;  // (16,16)
    t[ty][tx] = f[(size_t)(blockIdx.y*16 + ty) * 784 + blockIdx.x*16 + tx];
    __syncthreads();
    s[(size_t)(blockIdx.x*16 + ty) * 256 + blockIdx.y*16 + tx] = f2bf(t[tx][ty]);
}

// y[b*784+hw][d] bf16 -> out[b][d][h][w] fp32
__global__ __launch_bounds__(256) void from_seq_kernel(const u16* __restrict__ y,
                                                       float* __restrict__ out)
{
    __shared__ float t[16][17];
    int b = blockIdx.z;
    const u16* yb = y + (size_t)b * 784 * 256;
    float* ob = out + (size_t)b * 256 * 784;
    int tx = threadIdx.x, ty = threadIdx.y;
    t[ty][tx] = bf2f(yb[(size_t)(blockIdx.x*16 + ty) * 256 + blockIdx.y*16 + tx]);
    __syncthreads();
    ob[(size_t)(blockIdx.y*16 + ty) * 784 + blockIdx.x*16 + tx] = t[tx][ty];
}

// ---------------- host orchestration ----------------------------------------
extern "C" void kernel_launch(void* const* d_in, const int* in_sizes, int n_in,
                              void* d_out, int out_size, void* d_ws, size_t ws_size,
                              hipStream_t stream)
{
    (void)in_sizes; (void)n_in; (void)out_size; (void)ws_size;
    const float* f0 = (const float*)d_in[0];
    const float* f1 = (const float*)d_in[1];
    const float* f2 = (const float*)d_in[2];
    const float* f3 = (const float*)d_in[3];
    const float* Wq_a = (const float*)d_in[4];
    const float* Wk_a = (const float*)d_in[5];
    const float* Wv_a = (const float*)d_in[6];
    const float* Wq_b = (const float*)d_in[7];
    const float* Wk_b = (const float*)d_in[8];
    const float* Wv_b = (const float*)d_in[9];
    const float* bq_a = (const float*)d_in[10];
    const float* bk_a = (const float*)d_in[11];
    const float* bv_a = (const float*)d_in[12];
    const float* bq_b = (const float*)d_in[13];
    const float* bk_b = (const float*)d_in[14];
    const float* bv_b = (const float*)d_in[15];
    const float* gamma = (const float*)d_in[16];
    const float* gamma_ffn = (const float*)d_in[17];
    const float* Wfuse = (const float*)d_in[18];
    const float* bfuse = (const float*)d_in[19];
    const float* W1 = (const float*)d_in[20];
    const float* b1 = (const float*)d_in[21];
    const float* W2 = (const float*)d_in[22];
    const float* b2 = (const float*)d_in[23];
    const float* ln1_g = (const float*)d_in[24];
    const float* ln1_b = (const float*)d_in[25];
    const float* ln2_g = (const float*)d_in[26];
    const float* ln2_b = (const float*)d_in[27];
    const float* fp_ln_g = (const float*)d_in[28];
    const float* fp_ln_b = (const float*)d_in[29];
    const float* fp_W = (const float*)d_in[30];
    const float* fp_b = (const float*)d_in[31];
    const float* ff_ln_g = (const float*)d_in[32];
    const float* ff_ln_b = (const float*)d_in[33];
    const float* ff_W = (const float*)d_in[34];
    const float* ff_b = (const float*)d_in[35];
    const float* mha_Wqkv = (const float*)d_in[36];
    const float* mha_bqkv = (const float*)d_in[37];
    const float* mha_Wo = (const float*)d_in[38];
    const float* mha_bo = (const float*)d_in[39];
    const float* norm_g = (const float*)d_in[40];
    const float* norm_b = (const float*)d_in[41];

    u16* W = (u16*)d_ws;
    u16* projWt = W;                          // 24*65536 = 1572864
    u16* fuseWt = projWt + 1572864;           // 524288
    u16* W1t    = fuseWt + 524288;            // 1048576
    u16* W2t    = W1t + 1048576;              // 1048576
    u16* fpWt   = W2t + 1048576;              // 65536
    u16* ffWt   = fpWt + 65536;               // 262144
    u16* qkvWt  = ffWt + 262144;              // 196608
    u16* WoWt   = qkvWt + 196608;             // 65536
    float* biasc = (float*)(WoWt + 65536);    // 6144 floats
    u16* act    = (u16*)(biasc + 6144);

    u16* s     = act;               // 4 MD
    u16* e     = act + 4*MD;        // 4 MD
    u16* projc = act + 8*MD;        // 24 MD
    u16* vt    = act + 32*MD;       // 8 MD
    u16* fin   = act + 40*MD;       // 8 MD   (peak: 48 MD)
    // overlays (projc/vt dead at time of use)
    u16* ffh  = projc;              // 16 MD
    u16* fb   = projc + 16*MD;      // 4 MD
    u16* xa1  = projc + 20*MD;      // 4 MD
    u16* ffb  = vt;                 // 4 MD

    // input layout + weight pre-transpose
    to_seq_kernel<<<dim3(49,16,16), dim3(16,16), 0, stream>>>(f0,f1,f2,f3, s);
    transpose_w6<<<dim3(8,8,24), dim3(32,8), 0, stream>>>(Wq_a,Wk_a,Wv_a,Wq_b,Wk_b,Wv_b, projWt);
    pack_bias_kernel<<<24, 256, 0, stream>>>(bq_a,bk_a,bv_a,bq_b,bk_b,bv_b, biasc);
    transpose_w<<<dim3(8,16,4), dim3(32,8), 0, stream>>>(Wfuse, fuseWt, 512, 256);
    transpose_w<<<dim3(32,8,4), dim3(32,8), 0, stream>>>(W1, W1t, 256, 1024);
    transpose_w<<<dim3(8,32,4), dim3(32,8), 0, stream>>>(W2, W2t, 1024, 256);
    transpose_w<<<dim3(8,8,1),  dim3(32,8), 0, stream>>>(fp_W, fpWt, 256, 256);
    transpose_w<<<dim3(8,32,1), dim3(32,8), 0, stream>>>(ff_W, ffWt, 1024, 256);
    transpose_w<<<dim3(24,8,1), dim3(32,8), 0, stream>>>(mha_Wqkv, qkvWt, 256, 768);
    transpose_w<<<dim3(8,8,1),  dim3(32,8), 0, stream>>>(mha_Wo, WoWt, 256, 256);

    // two groups of 4 independent block invocations (a-side = s[inv]):
    // A = {bi0,bi2,bi4,bi6}: i={0,0,2,1}, b={1,0,1,0}, accum=0
    // B = {bi1,bi3,bi5,bi7}: i={1,2,3,3}, b={3,2,3,2}, accum=1
    const int GI[2][4] = {{0,0,2,1},{1,2,3,3}};
    const int GB[2][4] = {{1,0,1,0},{3,2,3,2}};

    for (int g = 0; g < 2; g++) {
        int i0 = GI[g][0], i1 = GI[g][1], i2 = GI[g][2], i3 = GI[g][3];
        proj8_kernel<<<dim3(49,12,8), 256, 0, stream>>>(s,
            GB[g][0], GB[g][1], GB[g][2], GB[g][3], i0, i1, i2, i3,
            projWt, biasc, projc);
        vtrans_kernel<<<dim3(13,32,8), 256, 0, stream>>>(projc, 0, vt);
        attn_pair_kernel<<<3328, 256, 0, stream>>>(projc, vt, fin);
        gemm2_kernel<<<dim3(49,4,4), 256, 0, stream>>>(fin, 512, (int)(2*MD),
            fuseWt, 512, i0, i1, i2, i3, 131072, bfuse, 256, fb, 256, (int)MD, 0);
        ln_kernel<<<dim3(784,4), 256, 0, stream>>>(fb, (int)MD,
            s, (int)MD, gamma, i0, i1, i2, i3, ln1_g, ln1_b, 256,
            xa1, (int)MD, 1.0f, 0, 256);
        gemm2_kernel<<<dim3(49,16,4), 256, 0, stream>>>(xa1, 256, (int)MD,
            W1t, 256, i0, i1, i2, i3, 262144, b1, 1024, ffh, 1024, (int)(4*MD), 1);
        gemm2_kernel<<<dim3(49,4,4), 256, 0, stream>>>(ffh, 1024, (int)(4*MD),
            W2t, 1024, i0, i1, i2, i3, 262144, b2, 256, ffb, 256, (int)MD, 0);
        ln_kernel<<<dim3(784,4), 256, 0, stream>>>(ffb, (int)MD,
            xa1, (int)MD, gamma_ffn, i0, i1, i2, i3, ln2_g, ln2_b, 256,
            e, (int)MD, 0.5f, g, 256);
    }

    // final fuse stage (reuse dead scratch; e live until first LN done)
    u16* ln4    = act + 8*MD;        // 4 MD
    u16* allf   = act + 12*MD;       // 4 MD  [3136][1024]
    u16* ffln   = act + 16*MD;       // 4 MD
    u16* x2     = act + 20*MD;       // 1 MD
    u16* qkv    = act + 21*MD;       // 3 MD  [3136][768]
    u16* vtmha  = act + 24*MD;       // 1 MD
    u16* attn_o = act + 25*MD;       // 1 MD
    u16* ymid   = act + 26*MD;       // 1 MD
    u16* yfin   = act + 27*MD;       // 1 MD

    ln_kernel<<<dim3(784,4), 256, 0, stream>>>(e, (int)MD,
        (const u16*)nullptr, 0, (const float*)nullptr, 0,0,0,0,
        fp_ln_g, fp_ln_b, 0, ln4, (int)MD, 1.0f, 0, 256);
    gemm2_kernel<<<dim3(49,4,4), 256, 0, stream>>>(ln4, 256, (int)MD,
        fpWt, 256, 0,0,0,0, 0, fp_b, 0, allf, 1024, 256, 1);
    ln_kernel<<<dim3(784,1), 256, 0, stream>>>(allf, 0,
        (const u16*)nullptr, 0, (const float*)nullptr, 0,0,0,0,
        ff_ln_g, ff_ln_b, 0, ffln, 0, 1.0f, 0, 1024);
    gemm2_kernel<<<dim3(49,4,1), 256, 0, stream>>>(ffln, 1024, 0,
        ffWt, 1024, 0,0,0,0, 0, ff_b, 0, x2, 256, 0, 1);
    gemm2_kernel<<<dim3(49,12,1), 256, 0, stream>>>(x2, 256, 0,
        qkvWt, 256, 0,0,0,0, 0, mha_bqkv, 0, qkv, 768, 0, 0);
    vtrans_kernel<<<dim3(13,32,1), 256, 0, stream>>>(qkv, 1, vtmha);
    attn_mha_kernel<<<416, 256, 0, stream>>>(qkv, vtmha, attn_o);
    gemm2_kernel<<<dim3(49,4,1), 256, 0, stream>>>(attn_o, 256, 0,
        WoWt, 256, 0,0,0,0, 0, mha_bo, 0, ymid, 256, 0, 0);
    ln_kernel<<<dim3(784,1), 256, 0, stream>>>(ymid, 0,
        (const u16*)nullptr, 0, (const float*)nullptr, 0,0,0,0,
        norm_g, norm_b, 0, yfin, 0, 1.0f, 0, 256);
    from_seq_kernel<<<dim3(49,16,4), dim3(16,16), 0, stream>>>(yfin, (float*)d_out);
}

// Round 6
// 487.393 us; speedup vs baseline: 1.2528x; 1.0544x over previous
//
#include <hip/hip_runtime.h>

typedef unsigned short u16;
typedef __bf16 bf16x8 __attribute__((ext_vector_type(8)));
typedef float f32x4 __attribute__((ext_vector_type(4)));
typedef unsigned short u16x8 __attribute__((ext_vector_type(8)));
typedef unsigned short u16x4 __attribute__((ext_vector_type(4)));

static constexpr size_t MD = 802816;   // 3136*256 elements

__device__ __forceinline__ u16 f2bf(float f) {
    __bf16 h = (__bf16)f;
    return __builtin_bit_cast(unsigned short, h);
}
__device__ __forceinline__ float bf2f(u16 u) {
    return __uint_as_float(((unsigned)u) << 16);
}
__device__ __forceinline__ float gelu_f(float x) {
    return 0.5f * x * (1.0f + erff(x * 0.70710678118654752f));
}
// pack two f32 -> two bf16 in one u32 (low = a, high = b)
__device__ __forceinline__ unsigned cvt_pk_bf16(float a, float b) {
    unsigned r;
    asm("v_cvt_pk_bf16_f32 %0, %1, %2" : "=v"(r) : "v"(a), "v"(b));
    return r;
}

// ------------- bf16 GEMM core, 64x64 tile, BK=64, swapped epilogue ----------
// A bf16 [3136 x K] (lda), Bt bf16 [N x K] row-major. Weights are the MFMA
// first operand so each lane's 4 acc elems are 4 consecutive C columns.
__device__ __forceinline__ void gemm_core(
    const u16* __restrict__ A, int lda,
    const u16* __restrict__ Bt, int K,
    const float* __restrict__ bias,
    u16* __restrict__ C, int ldc, int act)
{
    __shared__ u16 As[64][72];
    __shared__ u16 Bs[64][72];
    const int tid  = threadIdx.x;
    const int wave = tid >> 6, lane = tid & 63;
    const int wr = wave >> 1, wc = wave & 1;
    const int l16 = lane & 15, kg = lane >> 4, kb = kg * 8;
    const int m0 = blockIdx.x * 64, n0 = blockIdx.y * 64;
    const int srow = tid >> 2, scol = (tid & 3) * 16;

    f32x4 acc[2][2];   // [n-frag][m-frag]
#pragma unroll
    for (int j = 0; j < 2; j++)
#pragma unroll
        for (int i = 0; i < 2; i++) { f32x4 z = {0.f,0.f,0.f,0.f}; acc[j][i] = z; }

    const u16* ap = A + (size_t)(m0 + srow) * lda + scol;
    const u16* bp = Bt + (size_t)(n0 + srow) * K + scol;
    u16x8 ua0 = *(const u16x8*)ap;
    u16x8 ua1 = *(const u16x8*)(ap + 8);
    u16x8 ub0 = *(const u16x8*)bp;
    u16x8 ub1 = *(const u16x8*)(bp + 8);

    for (int kt = 0; kt < K; kt += 64) {
        *(u16x8*)&As[srow][scol]     = ua0;
        *(u16x8*)&As[srow][scol + 8] = ua1;
        *(u16x8*)&Bs[srow][scol]     = ub0;
        *(u16x8*)&Bs[srow][scol + 8] = ub1;
        __syncthreads();
        if (kt + 64 < K) {
            ua0 = *(const u16x8*)(ap + kt + 64);
            ua1 = *(const u16x8*)(ap + kt + 72);
            ub0 = *(const u16x8*)(bp + kt + 64);
            ub1 = *(const u16x8*)(bp + kt + 72);
        }
#pragma unroll
        for (int h = 0; h < 2; h++) {
            bf16x8 af[2], bf[2];
#pragma unroll
            for (int j = 0; j < 2; j++)
                af[j] = *(const bf16x8*)&Bs[wc*32 + j*16 + l16][h*32 + kb];
#pragma unroll
            for (int i = 0; i < 2; i++)
                bf[i] = *(const bf16x8*)&As[wr*32 + i*16 + l16][h*32 + kb];
#pragma unroll
            for (int j = 0; j < 2; j++)
#pragma unroll
                for (int i = 0; i < 2; i++)
                    acc[j][i] = __builtin_amdgcn_mfma_f32_16x16x32_bf16(
                        af[j], bf[i], acc[j][i], 0,0,0);
        }
        __syncthreads();
    }
#pragma unroll
    for (int j = 0; j < 2; j++) {
        int wcol = n0 + wc*32 + j*16 + kg*4;
        f32x4 bv = *(const f32x4*)&bias[wcol];
#pragma unroll
        for (int i = 0; i < 2; i++) {
            int row = m0 + wr*32 + i*16 + l16;
            u16x4 o;
#pragma unroll
            for (int r = 0; r < 4; r++) {
                float v = acc[j][i][r] + bv[r];
                if (act == 1) v = gelu_f(v);
                o[r] = f2bf(v);
            }
            *(u16x4*)&C[(size_t)row * ldc + wcol] = o;
        }
    }
}

// generic z-batched GEMM
__global__ __launch_bounds__(256) void gemm2_kernel(
    const u16* __restrict__ A, int lda, int zA,
    const u16* __restrict__ Bt, int K, int i0, int i1, int i2, int i3, int Bsz,
    const float* __restrict__ bias, int bN,
    u16* __restrict__ C, int ldc, int zC, int act)
{
    int z = blockIdx.z;
    int iz = (z == 0) ? i0 : (z == 1) ? i1 : (z == 2) ? i2 : i3;
    gemm_core(A + (size_t)z * zA, lda,
              Bt + (size_t)iz * Bsz, K,
              bias + (size_t)iz * bN,
              C + (size_t)z * zC, ldc, act);
}

// cat projections: z = inv*2 + ab; output [3136][768] (q|k|v) per (inv,ab)
__global__ __launch_bounds__(256) void proj8_kernel(
    const u16* __restrict__ s, int b0, int b1, int b2, int b3,
    int i0, int i1, int i2, int i3,
    const u16* __restrict__ projWt, const float* __restrict__ biasc,
    u16* __restrict__ projc)
{
    int z = blockIdx.z;
    int inv = z >> 1, ab = z & 1;
    int bi = (inv == 0) ? b0 : (inv == 1) ? b1 : (inv == 2) ? b2 : b3;
    int ii = (inv == 0) ? i0 : (inv == 1) ? i1 : (inv == 2) ? i2 : i3;
    const u16* A = s + (size_t)(ab ? bi : inv) * MD;
    int widx = ii * 2 + ab;
    gemm_core(A, 256, projWt + (size_t)widx * 768 * 256, 256,
              biasc + widx * 768,
              projc + (size_t)z * 3 * MD, 768, 0);
}

// biascat[(i*2+ab)*768 + (tsr%3)*256 + c] = barr[tsr][i*256+c];  z: tsr=z>>2,i=z&3
__global__ __launch_bounds__(256) void pack_bias_kernel(
    const float* b0, const float* b1, const float* b2,
    const float* b3, const float* b4, const float* b5,
    float* __restrict__ biasc)
{
    int z = blockIdx.x;
    int tsr = z >> 2, i = z & 3;
    const float* barr[6] = {b0,b1,b2,b3,b4,b5};
    int ab = (tsr >= 3) ? 1 : 0;
    biasc[(i*2 + ab)*768 + (tsr % 3)*256 + threadIdx.x] = barr[tsr][i*256 + threadIdx.x];
}

// ---------------- flash attention core (bf16, Vt pre-transposed) ------------
// Two 64-k sub-tiles per barrier pair (independent chains -> 2x ILP).
// Q pre-scaled by scale*log2e; p = exp2(s). l via ones-row MFMA.
__device__ __forceinline__ void attn2_core(
    const u16* __restrict__ Qg, int ldq,
    const u16* __restrict__ Kg, int ldk,
    const u16* __restrict__ Vtg,          // [32 d][784 k] for this (b,h)
    u16* __restrict__ Og, int ldo,
    int qt, int rowbase, int qkcol, int ocol)
{
    __shared__ u16 Qs[64][40];
    __shared__ u16 Ks[2][64][40];
    __shared__ u16 Vts[2][48][72];        // rows 0..31 = V^T, row 32 = ones
    __shared__ u16 Ps[4][2][16][84];      // [wave][sub][q][k(64) pad84]
    const int tid = threadIdx.x, wave = tid >> 6, lane = tid & 63;
    const int l16 = lane & 15, kg = lane >> 4, kb = kg * 8;
    const int sr = tid >> 2, sc8 = (tid & 3) * 8;
    const int vd = tid >> 3, vk8 = (tid & 7) * 8;
    const float QSC = 0.25503489f;        // 32^-0.5 * log2(e)

    {   // stage Q, pre-scaled
        int qrow = qt * 64 + sr;
        u16x8 u = {0,0,0,0,0,0,0,0};
        if (qrow < 784)
            u = *(const u16x8*)(Qg + (size_t)(rowbase + qrow) * ldq + qkcol + sc8);
#pragma unroll
        for (int j = 0; j < 8; j++) u[j] = f2bf(bf2f(u[j]) * QSC);
        *(u16x8*)&Qs[sr][sc8] = u;
    }
    // init ones/zero rows 32..47 of both V buffers (row 32 = bf16 1.0)
    for (int i = tid; i < 2*16*72; i += 256) {
        int b = (i >= 16*72);
        int rem = b ? i - 16*72 : i;
        int rr = rem / 72, cc = rem - rr*72;
        Vts[b][32 + rr][cc] = (rr == 0) ? (u16)0x3F80 : (u16)0;
    }
    {   // tiles 0,1 direct (rows < 128 < 784, no guards)
#pragma unroll
        for (int s2 = 0; s2 < 2; ++s2) {
            u16x8 k0 = *(const u16x8*)(Kg + (size_t)(rowbase + s2*64 + sr) * ldk + qkcol + sc8);
            u16x8 v0 = *(const u16x8*)(Vtg + (size_t)vd * 784 + s2*64 + vk8);
            *(u16x8*)&Ks[s2][sr][sc8] = k0;
            *(u16x8*)&Vts[s2][vd][vk8] = v0;
        }
    }
    __syncthreads();
    bf16x8 qfrag = *(const bf16x8*)&Qs[wave*16 + l16][kb];

    f32x4 oacc[3];
    { f32x4 z = {0.f,0.f,0.f,0.f}; oacc[0] = z; oacc[1] = z; oacc[2] = z; }

    u16x8 kr[2], vr[2];
    for (int pp = 0; pp < 6; ++pp) {
        // prefetch tiles 2pp+2, 2pp+3 into regs (tile 13 doesn't exist -> zeros)
#pragma unroll
        for (int s2 = 0; s2 < 2; ++s2) {
            u16x8 z8 = {0,0,0,0,0,0,0,0}; kr[s2] = z8; vr[s2] = z8;
            int tt = pp*2 + 2 + s2;
            if (tt < 13) {
                int krow = tt*64 + sr;
                if (krow < 784)
                    kr[s2] = *(const u16x8*)(Kg + (size_t)(rowbase + krow) * ldk + qkcol + sc8);
                int kc = tt*64 + vk8;
                if (kc + 7 < 784)
                    vr[s2] = *(const u16x8*)(Vtg + (size_t)vd * 784 + kc);
            }
        }
        // S^T for both sub-tiles (8 independent MFMAs)
        f32x4 sf[2][4];
#pragma unroll
        for (int s2 = 0; s2 < 2; ++s2)
#pragma unroll
            for (int n = 0; n < 4; n++) {
                bf16x8 kf = *(const bf16x8*)&Ks[s2][n*16 + l16][kb];
                f32x4 z = {0.f,0.f,0.f,0.f};
                sf[s2][n] = __builtin_amdgcn_mfma_f32_16x16x32_bf16(kf, qfrag, z, 0,0,0);
            }
        // p = 2^s for both (lane holds 4 consecutive k for q=l16 -> b64 store)
#pragma unroll
        for (int s2 = 0; s2 < 2; ++s2)
#pragma unroll
            for (int n = 0; n < 4; n++) {
                union { unsigned u[2]; u16x4 v; } pk;
                pk.u[0] = cvt_pk_bf16(exp2f(sf[s2][n][0]), exp2f(sf[s2][n][1]));
                pk.u[1] = cvt_pk_bf16(exp2f(sf[s2][n][2]), exp2f(sf[s2][n][3]));
                *(u16x4*)&Ps[wave][s2][l16][n*16 + kg*4] = pk.v;
            }
        // PV + ones-row (l) for both sub-tiles
#pragma unroll
        for (int s2 = 0; s2 < 2; ++s2)
#pragma unroll
            for (int c = 0; c < 2; c++) {
                bf16x8 pf = *(const bf16x8*)&Ps[wave][s2][l16][c*32 + kb];
#pragma unroll
                for (int n2 = 0; n2 < 3; n2++) {
                    bf16x8 vf = *(const bf16x8*)&Vts[s2][n2*16 + l16][c*32 + kb];
                    oacc[n2] = __builtin_amdgcn_mfma_f32_16x16x32_bf16(pf, vf, oacc[n2], 0,0,0);
                }
            }
        __syncthreads();
        *(u16x8*)&Ks[0][sr][sc8] = kr[0];
        *(u16x8*)&Ks[1][sr][sc8] = kr[1];
        *(u16x8*)&Vts[0][vd][vk8] = vr[0];
        *(u16x8*)&Vts[1][vd][vk8] = vr[1];
        __syncthreads();
    }
    {   // final tile 12 (16 valid k) in slot 0
        f32x4 sf[4];
#pragma unroll
        for (int n = 0; n < 4; n++) {
            bf16x8 kf = *(const bf16x8*)&Ks[0][n*16 + l16][kb];
            f32x4 z = {0.f,0.f,0.f,0.f};
            sf[n] = __builtin_amdgcn_mfma_f32_16x16x32_bf16(kf, qfrag, z, 0,0,0);
        }
#pragma unroll
        for (int n = 0; n < 4; n++) {
            union { unsigned u[2]; u16x4 v; } pk;
            if (n > 0) { pk.u[0] = 0; pk.u[1] = 0; }
            else {
                pk.u[0] = cvt_pk_bf16(exp2f(sf[n][0]), exp2f(sf[n][1]));
                pk.u[1] = cvt_pk_bf16(exp2f(sf[n][2]), exp2f(sf[n][3]));
            }
            *(u16x4*)&Ps[wave][0][l16][n*16 + kg*4] = pk.v;
        }
#pragma unroll
        for (int c = 0; c < 2; c++) {
            bf16x8 pf = *(const bf16x8*)&Ps[wave][0][l16][c*32 + kb];
#pragma unroll
            for (int n2 = 0; n2 < 3; n2++) {
                bf16x8 vf = *(const bf16x8*)&Vts[0][n2*16 + l16][c*32 + kb];
                oacc[n2] = __builtin_amdgcn_mfma_f32_16x16x32_bf16(pf, vf, oacc[n2], 0,0,0);
            }
        }
    }
    const int srcl = lane & 48;
    float rl[4];
#pragma unroll
    for (int r = 0; r < 4; r++) {
        float lsum = __shfl(oacc[2][r], srcl);
        rl[r] = __builtin_amdgcn_rcpf(lsum);
    }
#pragma unroll
    for (int n2 = 0; n2 < 2; n2++)
#pragma unroll
        for (int r = 0; r < 4; r++) {
            int row = qt*64 + wave*16 + kg*4 + r;
            if (row < 784)
                Og[(size_t)(rowbase + row) * ldo + ocol + n2*16 + l16] =
                    f2bf(oacc[n2][r] * rl[r]);
        }
}

// group-of-4 attention: 3328 blocks; z = inv*2 + dir (Q side = dir, K/V = dir^1)
__global__ __launch_bounds__(256) void attn_pair_kernel(
    const u16* __restrict__ projc, const u16* __restrict__ vt,
    u16* __restrict__ fusedin)
{
    int id = blockIdx.x;
    int wg = (id & 7) * 416 + (id >> 3);      // 3328/8 = 416
    int qt = wg % 13, bh = (wg / 13) & 31, z = wg / (13*32);
    int inv = z >> 1, dir = z & 1;
    const u16* Q  = projc + (size_t)z * 3 * MD;
    const u16* K  = projc + (size_t)(z ^ 1) * 3 * MD + 256;
    const u16* Vt = vt + (size_t)z * MD + (size_t)bh * 32 * 784;
    u16* O = fusedin + (size_t)inv * 2 * MD;
    int bb = bh >> 3, hh = bh & 7;
    attn2_core(Q, 768, K, 768, Vt, O, 512, qt, bb*784, hh*32, dir*256 + hh*32);
}

__global__ __launch_bounds__(256) void attn_mha_kernel(
    const u16* __restrict__ qkv, const u16* __restrict__ vtmha,
    u16* __restrict__ outp)
{
    int id = blockIdx.x;
    int wg = (id & 7) * 52 + (id >> 3);       // 416/8 = 52
    int qt = wg % 13, bh = wg / 13;
    int bb = bh >> 3, hh = bh & 7;
    const u16* Vt = vtmha + (size_t)bh * 32 * 784;
    attn2_core(qkv, 768, qkv + 256, 768, Vt, outp, 256, qt, bb*784, hh*32, hh*32);
}

// ---------------- LayerNorm (bf16 io): out = [prev +] os*(LN(res + tg*x)) ---
__global__ __launch_bounds__(256) void ln_kernel(
    const u16* __restrict__ x, int zx,
    const u16* __restrict__ res, int zres,
    const float* __restrict__ gamma, int i0, int i1, int i2, int i3,
    const float* __restrict__ g, const float* __restrict__ beta, int gN,
    u16* __restrict__ out, int zout,
    float outscale, int accum, int D)
{
    int z = blockIdx.y;
    int iz = (z == 0) ? i0 : (z == 1) ? i1 : (z == 2) ? i2 : i3;
    const u16* xb = x + (size_t)z * zx;
    const u16* rb = res ? res + (size_t)z * zres : (const u16*)nullptr;
    u16* ob = out + (size_t)z * zout;
    const float* gg = g + iz * gN;
    const float* bb = beta + iz * gN;
    int wave = threadIdx.x >> 6, lane = threadIdx.x & 63;
    size_t row = (size_t)blockIdx.x * 4 + wave;
    float tg = gamma ? tanhf(gamma[iz]) : 1.0f;
    const u16* xr = xb + row * D;
    const u16* rr = rb ? rb + row * D : (const u16*)nullptr;
    float vals[16];
    int nch = D >> 8;
    float s = 0.f, s2 = 0.f;
    for (int c = 0; c < nch; c++) {
        int col = c * 256 + lane * 4;
        u16x4 v = *(const u16x4*)(xr + col);
#pragma unroll
        for (int j = 0; j < 4; j++) {
            float a = tg * bf2f(v[j]);
            if (rr) a += bf2f(rr[col + j]);
            vals[c*4 + j] = a;
            s += a; s2 += a * a;
        }
    }
    for (int off = 1; off < 64; off <<= 1) {
        s  += __shfl_xor(s, off);
        s2 += __shfl_xor(s2, off);
    }
    float inv = 1.0f / D;
    float mean = s * inv;
    float var = s2 * inv - mean * mean;
    float rstd = rsqrtf(var + 1e-5f);
    for (int c = 0; c < nch; c++) {
        int col = c * 256 + lane * 4;
#pragma unroll
        for (int j = 0; j < 4; j++) {
            float o = (vals[c*4 + j] - mean) * rstd * gg[col + j] + bb[col + j];
            o *= outscale;
            if (accum) o += bf2f(ob[row*D + col + j]);
            ob[row*D + col + j] = f2bf(o);
        }
    }
}

// ---------------- layout kernels --------------------------------------------
__device__ __forceinline__ void transpose_body(const float* in, u16* out, int K, int N)
{
    __shared__ float t[32][33];
    int tx = threadIdx.x, ty = threadIdx.y;   // (32,8)
#pragma unroll
    for (int j = 0; j < 4; j++)
        t[ty + j*8][tx] = in[(size_t)(blockIdx.y*32 + ty + j*8) * N + blockIdx.x*32 + tx];
    __syncthreads();
#pragma unroll
    for (int j = 0; j < 4; j++)
        out[(size_t)(blockIdx.x*32 + ty + j*8) * K + blockIdx.y*32 + tx] =
            f2bf(t[tx][ty + j*8]);
}

__global__ __launch_bounds__(256) void transpose_w(const float* __restrict__ in,
                                                   u16* __restrict__ out, int K, int N)
{
    int z = blockIdx.z;
    transpose_body(in + (size_t)z * K * N, out + (size_t)z * K * N, K, N);
}

// proj weights into cat layout: [i][ab][768 n][256 k]
__global__ __launch_bounds__(256) void transpose_w6(
    const float* w0, const float* w1, const float* w2,
    const float* w3, const float* w4, const float* w5,
    u16* __restrict__ out)
{
    int z = blockIdx.z;           // 0..23: tsr = z/4, i = z%4
    int tsr = z >> 2, i = z & 3;
    const float* ws[6] = {w0,w1,w2,w3,w4,w5};
    int ab = (tsr >= 3) ? 1 : 0;
    u16* ob = out + (size_t)((i*2 + ab)*3 + (tsr % 3)) * 65536;
    transpose_body(ws[tsr] + (size_t)i * 65536, ob, 256, 256);
}

// transpose V (cols 512..767 of a 768-wide qkv buffer) -> [z][bh*32+d][784]
// mode 0: in = base + (z^1)*3MD + 512;  mode 1: in = base + 512 (z=0)
__global__ __launch_bounds__(256) void vtrans_kernel(
    const u16* __restrict__ base, int mode,
    u16* __restrict__ outbase)
{
    __shared__ u16 t[64][44];
    int z = blockIdx.z;
    size_t off = (mode ? (size_t)0 : (size_t)(z ^ 1) * 3 * MD) + 512;
    const u16* in = base + off;
    u16* out = outbase + (size_t)z * MD;
    int kt = blockIdx.x, bh = blockIdx.y;
    int bb = bh >> 3, hh = bh & 7;
    int tid = threadIdx.x;
    {
        int r = tid >> 2, c8 = (tid & 3) * 8;
        int krow = kt*64 + r;
        u16x8 u = {0,0,0,0,0,0,0,0};
        if (krow < 784)
            u = *(const u16x8*)(in + (size_t)(bb*784 + krow) * 768 + hh*32 + c8);
        *(u16x8*)&t[r][c8] = u;
    }
    __syncthreads();
    int d = tid >> 3, k8 = (tid & 7) * 8;
    if (kt*64 + k8 + 7 < 784) {
        u16x8 u;
#pragma unroll
        for (int j = 0; j < 8; j++) u[j] = t[k8 + j][d];
        *(u16x8*)&out[(size_t)(bh*32 + d) * 784 + kt*64 + k8] = u;
    }
}

// f[B,256,28,28] fp32 -> s[fi][b*784+hw][d] bf16
__global__ __launch_bounds__(256) void to_seq_kernel(
    const float* f0, const float* f1, const float* f2, const float* f3,
    u16* __restrict__ sbase)
{
    __shared__ float t[16][17];
    int z = blockIdx.z;
    int fi = z & 3, b = z >> 2;
    const float* fs[4] = {f0,f1,f2,f3};
    const float* f = fs[fi] + (size_t)b * 256 * 784;
    u16* s = sbase + (size_t)fi * MD + (size_t)b * 784 * 256;
    int tx = threadIdx.x, ty = threadIdx.y;  // (16,16)
    t[ty][tx] = f[(size_t)(blockIdx.y*16 + ty) * 784 + blockIdx.x*16 + tx];
    __syncthreads();
    s[(size_t)(blockIdx.x*16 + ty) * 256 + blockIdx.y*16 + tx] = f2bf(t[tx][ty]);
}

// y[b*784+hw][d] bf16 -> out[b][d][h][w] fp32
__global__ __launch_bounds__(256) void from_seq_kernel(const u16* __restrict__ y,
                                                       float* __restrict__ out)
{
    __shared__ float t[16][17];
    int b = blockIdx.z;
    const u16* yb = y + (size_t)b * 784 * 256;
    float* ob = out + (size_t)b * 256 * 784;
    int tx = threadIdx.x, ty = threadIdx.y;
    t[ty][tx] = bf2f(yb[(size_t)(blockIdx.x*16 + ty) * 256 + blockIdx.y*16 + tx]);
    __syncthreads();
    ob[(size_t)(blockIdx.y*16 + ty) * 784 + blockIdx.x*16 + tx] = t[tx][ty];
}

// ---------------- host orchestration ----------------------------------------
extern "C" void kernel_launch(void* const* d_in, const int* in_sizes, int n_in,
                              void* d_out, int out_size, void* d_ws, size_t ws_size,
                              hipStream_t stream)
{
    (void)in_sizes; (void)n_in; (void)out_size; (void)ws_size;
    const float* f0 = (const float*)d_in[0];
    const float* f1 = (const float*)d_in[1];
    const float* f2 = (const float*)d_in[2];
    const float* f3 = (const float*)d_in[3];
    const float* Wq_a = (const float*)d_in[4];
    const float* Wk_a = (const float*)d_in[5];
    const float* Wv_a = (const float*)d_in[6];
    const float* Wq_b = (const float*)d_in[7];
    const float* Wk_b = (const float*)d_in[8];
    const float* Wv_b = (const float*)d_in[9];
    const float* bq_a = (const float*)d_in[10];
    const float* bk_a = (const float*)d_in[11];
    const float* bv_a = (const float*)d_in[12];
    const float* bq_b = (const float*)d_in[13];
    const float* bk_b = (const float*)d_in[14];
    const float* bv_b = (const float*)d_in[15];
    const float* gamma = (const float*)d_in[16];
    const float* gamma_ffn = (const float*)d_in[17];
    const float* Wfuse = (const float*)d_in[18];
    const float* bfuse = (const float*)d_in[19];
    const float* W1 = (const float*)d_in[20];
    const float* b1 = (const float*)d_in[21];
    const float* W2 = (const float*)d_in[22];
    const float* b2 = (const float*)d_in[23];
    const float* ln1_g = (const float*)d_in[24];
    const float* ln1_b = (const float*)d_in[25];
    const float* ln2_g = (const float*)d_in[26];
    const float* ln2_b = (const float*)d_in[27];
    const float* fp_ln_g = (const float*)d_in[28];
    const float* fp_ln_b = (const float*)d_in[29];
    const float* fp_W = (const float*)d_in[30];
    const float* fp_b = (const float*)d_in[31];
    const float* ff_ln_g = (const float*)d_in[32];
    const float* ff_ln_b = (const float*)d_in[33];
    const float* ff_W = (const float*)d_in[34];
    const float* ff_b = (const float*)d_in[35];
    const float* mha_Wqkv = (const float*)d_in[36];
    const float* mha_bqkv = (const float*)d_in[37];
    const float* mha_Wo = (const float*)d_in[38];
    const float* mha_bo = (const float*)d_in[39];
    const float* norm_g = (const float*)d_in[40];
    const float* norm_b = (const float*)d_in[41];

    u16* W = (u16*)d_ws;
    u16* projWt = W;                          // 24*65536 = 1572864
    u16* fuseWt = projWt + 1572864;           // 524288
    u16* W1t    = fuseWt + 524288;            // 1048576
    u16* W2t    = W1t + 1048576;              // 1048576
    u16* fpWt   = W2t + 1048576;              // 65536
    u16* ffWt   = fpWt + 65536;               // 262144
    u16* qkvWt  = ffWt + 262144;              // 196608
    u16* WoWt   = qkvWt + 196608;             // 65536
    float* biasc = (float*)(WoWt + 65536);    // 6144 floats
    u16* act    = (u16*)(biasc + 6144);

    u16* s     = act;               // 4 MD
    u16* e     = act + 4*MD;        // 4 MD
    u16* projc = act + 8*MD;        // 24 MD
    u16* vt    = act + 32*MD;       // 8 MD
    u16* fin   = act + 40*MD;       // 8 MD   (peak: 48 MD)
    // overlays (projc/vt dead at time of use)
    u16* ffh  = projc;              // 16 MD
    u16* fb   = projc + 16*MD;      // 4 MD
    u16* xa1  = projc + 20*MD;      // 4 MD
    u16* ffb  = vt;                 // 4 MD

    // input layout + weight pre-transpose
    to_seq_kernel<<<dim3(49,16,16), dim3(16,16), 0, stream>>>(f0,f1,f2,f3, s);
    transpose_w6<<<dim3(8,8,24), dim3(32,8), 0, stream>>>(Wq_a,Wk_a,Wv_a,Wq_b,Wk_b,Wv_b, projWt);
    pack_bias_kernel<<<24, 256, 0, stream>>>(bq_a,bk_a,bv_a,bq_b,bk_b,bv_b, biasc);
    transpose_w<<<dim3(8,16,4), dim3(32,8), 0, stream>>>(Wfuse, fuseWt, 512, 256);
    transpose_w<<<dim3(32,8,4), dim3(32,8), 0, stream>>>(W1, W1t, 256, 1024);
    transpose_w<<<dim3(8,32,4), dim3(32,8), 0, stream>>>(W2, W2t, 1024, 256);
    transpose_w<<<dim3(8,8,1),  dim3(32,8), 0, stream>>>(fp_W, fpWt, 256, 256);
    transpose_w<<<dim3(8,32,1), dim3(32,8), 0, stream>>>(ff_W, ffWt, 1024, 256);
    transpose_w<<<dim3(24,8,1), dim3(32,8), 0, stream>>>(mha_Wqkv, qkvWt, 256, 768);
    transpose_w<<<dim3(8,8,1),  dim3(32,8), 0, stream>>>(mha_Wo, WoWt, 256, 256);

    // two groups of 4 independent block invocations (a-side = s[inv]):
    // A = {bi0,bi2,bi4,bi6}: i={0,0,2,1}, b={1,0,1,0}, accum=0
    // B = {bi1,bi3,bi5,bi7}: i={1,2,3,3}, b={3,2,3,2}, accum=1
    const int GI[2][4] = {{0,0,2,1},{1,2,3,3}};
    const int GB[2][4] = {{1,0,1,0},{3,2,3,2}};

    for (int g = 0; g < 2; g++) {
        int i0 = GI[g][0], i1 = GI[g][1], i2 = GI[g][2], i3 = GI[g][3];
        proj8_kernel<<<dim3(49,12,8), 256, 0, stream>>>(s,
            GB[g][0], GB[g][1], GB[g][2], GB[g][3], i0, i1, i2, i3,
            projWt, biasc, projc);
        vtrans_kernel<<<dim3(13,32,8), 256, 0, stream>>>(projc, 0, vt);
        attn_pair_kernel<<<3328, 256, 0, stream>>>(projc, vt, fin);
        gemm2_kernel<<<dim3(49,4,4), 256, 0, stream>>>(fin, 512, (int)(2*MD),
            fuseWt, 512, i0, i1, i2, i3, 131072, bfuse, 256, fb, 256, (int)MD, 0);
        ln_kernel<<<dim3(784,4), 256, 0, stream>>>(fb, (int)MD,
            s, (int)MD, gamma, i0, i1, i2, i3, ln1_g, ln1_b, 256,
            xa1, (int)MD, 1.0f, 0, 256);
        gemm2_kernel<<<dim3(49,16,4), 256, 0, stream>>>(xa1, 256, (int)MD,
            W1t, 256, i0, i1, i2, i3, 262144, b1, 1024, ffh, 1024, (int)(4*MD), 1);
        gemm2_kernel<<<dim3(49,4,4), 256, 0, stream>>>(ffh, 1024, (int)(4*MD),
            W2t, 1024, i0, i1, i2, i3, 262144, b2, 256, ffb, 256, (int)MD, 0);
        ln_kernel<<<dim3(784,4), 256, 0, stream>>>(ffb, (int)MD,
            xa1, (int)MD, gamma_ffn, i0, i1, i2, i3, ln2_g, ln2_b, 256,
            e, (int)MD, 0.5f, g, 256);
    }

    // final fuse stage (reuse dead scratch; e live until first LN done)
    u16* ln4    = act + 8*MD;        // 4 MD
    u16* allf   = act + 12*MD;       // 4 MD  [3136][1024]
    u16* ffln   = act + 16*MD;       // 4 MD
    u16* x2     = act + 20*MD;       // 1 MD
    u16* qkv    = act + 21*MD;       // 3 MD  [3136][768]
    u16* vtmha  = act + 24*MD;       // 1 MD
    u16* attn_o = act + 25*MD;       // 1 MD
    u16* ymid   = act + 26*MD;       // 1 MD
    u16* yfin   = act + 27*MD;       // 1 MD

    ln_kernel<<<dim3(784,4), 256, 0, stream>>>(e, (int)MD,
        (const u16*)nullptr, 0, (const float*)nullptr, 0,0,0,0,
        fp_ln_g, fp_ln_b, 0, ln4, (int)MD, 1.0f, 0, 256);
    gemm2_kernel<<<dim3(49,4,4), 256, 0, stream>>>(ln4, 256, (int)MD,
        fpWt, 256, 0,0,0,0, 0, fp_b, 0, allf, 1024, 256, 1);
    ln_kernel<<<dim3(784,1), 256, 0, stream>>>(allf, 0,
        (const u16*)nullptr, 0, (const float*)nullptr, 0,0,0,0,
        ff_ln_g, ff_ln_b, 0, ffln, 0, 1.0f, 0, 1024);
    gemm2_kernel<<<dim3(49,4,1), 256, 0, stream>>>(ffln, 1024, 0,
        ffWt, 1024, 0,0,0,0, 0, ff_b, 0, x2, 256, 0, 1);
    gemm2_kernel<<<dim3(49,12,1), 256, 0, stream>>>(x2, 256, 0,
        qkvWt, 256, 0,0,0,0, 0, mha_bqkv, 0, qkv, 768, 0, 0);
    vtrans_kernel<<<dim3(13,32,1), 256, 0, stream>>>(qkv, 1, vtmha);
    attn_mha_kernel<<<416, 256, 0, stream>>>(qkv, vtmha, attn_o);
    gemm2_kernel<<<dim3(49,4,1), 256, 0, stream>>>(attn_o, 256, 0,
        WoWt, 256, 0,0,0,0, 0, mha_bo, 0, ymid, 256, 0, 0);
    ln_kernel<<<dim3(784,1), 256, 0, stream>>>(ymid, 0,
        (const u16*)nullptr, 0, (const float*)nullptr, 0,0,0,0,
        norm_g, norm_b, 0, yfin, 0, 1.0f, 0, 256);
    from_seq_kernel<<<dim3(49,16,4), dim3(16,16), 0, stream>>>(yfin, (float*)d_out);
}

// Round 7
// 485.975 us; speedup vs baseline: 1.2565x; 1.0029x over previous
//
#include <hip/hip_runtime.h>

typedef unsigned short u16;
typedef __bf16 bf16x8 __attribute__((ext_vector_type(8)));
typedef float f32x4 __attribute__((ext_vector_type(4)));
typedef float f32x16 __attribute__((ext_vector_type(16)));
typedef unsigned short u16x8 __attribute__((ext_vector_type(8)));
typedef unsigned short u16x4 __attribute__((ext_vector_type(4)));

static constexpr size_t MD = 802816;   // 3136*256 elements

__device__ __forceinline__ u16 f2bf(float f) {
    __bf16 h = (__bf16)f;
    return __builtin_bit_cast(unsigned short, h);
}
__device__ __forceinline__ float bf2f(u16 u) {
    return __uint_as_float(((unsigned)u) << 16);
}
__device__ __forceinline__ float gelu_f(float x) {
    return 0.5f * x * (1.0f + erff(x * 0.70710678118654752f));
}
// pack two f32 -> two bf16 in one u32 (low = a, high = b)
__device__ __forceinline__ unsigned cvt_pk_bf16(float a, float b) {
    unsigned r;
    asm("v_cvt_pk_bf16_f32 %0, %1, %2" : "=v"(r) : "v"(a), "v"(b));
    return r;
}
union u8_4 { u16x8 v8; u16x4 v4[2]; };
union bf8_4 { bf16x8 f; u16x4 h[2]; };

// ------------- bf16 GEMM core, 64x64 tile, BK=64, swapped epilogue ----------
__device__ __forceinline__ void gemm_core(
    const u16* __restrict__ A, int lda,
    const u16* __restrict__ Bt, int K,
    const float* __restrict__ bias,
    u16* __restrict__ C, int ldc, int act)
{
    __shared__ u16 As[64][72];
    __shared__ u16 Bs[64][72];
    const int tid  = threadIdx.x;
    const int wave = tid >> 6, lane = tid & 63;
    const int wr = wave >> 1, wc = wave & 1;
    const int l16 = lane & 15, kg = lane >> 4, kb = kg * 8;
    const int m0 = blockIdx.x * 64, n0 = blockIdx.y * 64;
    const int srow = tid >> 2, scol = (tid & 3) * 16;

    f32x4 acc[2][2];   // [n-frag][m-frag]
#pragma unroll
    for (int j = 0; j < 2; j++)
#pragma unroll
        for (int i = 0; i < 2; i++) { f32x4 z = {0.f,0.f,0.f,0.f}; acc[j][i] = z; }

    const u16* ap = A + (size_t)(m0 + srow) * lda + scol;
    const u16* bp = Bt + (size_t)(n0 + srow) * K + scol;
    u16x8 ua0 = *(const u16x8*)ap;
    u16x8 ua1 = *(const u16x8*)(ap + 8);
    u16x8 ub0 = *(const u16x8*)bp;
    u16x8 ub1 = *(const u16x8*)(bp + 8);

    for (int kt = 0; kt < K; kt += 64) {
        *(u16x8*)&As[srow][scol]     = ua0;
        *(u16x8*)&As[srow][scol + 8] = ua1;
        *(u16x8*)&Bs[srow][scol]     = ub0;
        *(u16x8*)&Bs[srow][scol + 8] = ub1;
        __syncthreads();
        if (kt + 64 < K) {
            ua0 = *(const u16x8*)(ap + kt + 64);
            ua1 = *(const u16x8*)(ap + kt + 72);
            ub0 = *(const u16x8*)(bp + kt + 64);
            ub1 = *(const u16x8*)(bp + kt + 72);
        }
#pragma unroll
        for (int h = 0; h < 2; h++) {
            bf16x8 af[2], bf[2];
#pragma unroll
            for (int j = 0; j < 2; j++)
                af[j] = *(const bf16x8*)&Bs[wc*32 + j*16 + l16][h*32 + kb];
#pragma unroll
            for (int i = 0; i < 2; i++)
                bf[i] = *(const bf16x8*)&As[wr*32 + i*16 + l16][h*32 + kb];
#pragma unroll
            for (int j = 0; j < 2; j++)
#pragma unroll
                for (int i = 0; i < 2; i++)
                    acc[j][i] = __builtin_amdgcn_mfma_f32_16x16x32_bf16(
                        af[j], bf[i], acc[j][i], 0,0,0);
        }
        __syncthreads();
    }
#pragma unroll
    for (int j = 0; j < 2; j++) {
        int wcol = n0 + wc*32 + j*16 + kg*4;
        f32x4 bv = *(const f32x4*)&bias[wcol];
#pragma unroll
        for (int i = 0; i < 2; i++) {
            int row = m0 + wr*32 + i*16 + l16;
            u16x4 o;
#pragma unroll
            for (int r = 0; r < 4; r++) {
                float v = acc[j][i][r] + bv[r];
                if (act == 1) v = gelu_f(v);
                o[r] = f2bf(v);
            }
            *(u16x4*)&C[(size_t)row * ldc + wcol] = o;
        }
    }
}

// generic z-batched GEMM
__global__ __launch_bounds__(256) void gemm2_kernel(
    const u16* __restrict__ A, int lda, int zA,
    const u16* __restrict__ Bt, int K, int i0, int i1, int i2, int i3, int Bsz,
    const float* __restrict__ bias, int bN,
    u16* __restrict__ C, int ldc, int zC, int act)
{
    int z = blockIdx.z;
    int iz = (z == 0) ? i0 : (z == 1) ? i1 : (z == 2) ? i2 : i3;
    gemm_core(A + (size_t)z * zA, lda,
              Bt + (size_t)iz * Bsz, K,
              bias + (size_t)iz * bN,
              C + (size_t)z * zC, ldc, act);
}

// cat projections: z = inv*2 + ab; output [3136][768] (q|k|v) per (inv,ab)
__global__ __launch_bounds__(256) void proj8_kernel(
    const u16* __restrict__ s, int b0, int b1, int b2, int b3,
    int i0, int i1, int i2, int i3,
    const u16* __restrict__ projWt, const float* __restrict__ biasc,
    u16* __restrict__ projc)
{
    int z = blockIdx.z;
    int inv = z >> 1, ab = z & 1;
    int bi = (inv == 0) ? b0 : (inv == 1) ? b1 : (inv == 2) ? b2 : b3;
    int ii = (inv == 0) ? i0 : (inv == 1) ? i1 : (inv == 2) ? i2 : i3;
    const u16* A = s + (size_t)(ab ? bi : inv) * MD;
    int widx = ii * 2 + ab;
    gemm_core(A, 256, projWt + (size_t)widx * 768 * 256, 256,
              biasc + widx * 768,
              projc + (size_t)z * 3 * MD, 768, 0);
}

__global__ __launch_bounds__(256) void pack_bias_kernel(
    const float* b0, const float* b1, const float* b2,
    const float* b3, const float* b4, const float* b5,
    float* __restrict__ biasc)
{
    int z = blockIdx.x;
    int tsr = z >> 2, i = z & 3;
    const float* barr[6] = {b0,b1,b2,b3,b4,b5};
    int ab = (tsr >= 3) ? 1 : 0;
    biasc[(i*2 + ab)*768 + (tsr % 3)*256 + threadIdx.x] = barr[tsr][i*256 + threadIdx.x];
}

// ---------------- flash attention core, 32x32x16 MFMA, 32 q-rows/wave -------
// QBLK=128 (4 waves). S^T = mfma32(K, Q): lane holds 16 P vals for q=lane&31
// -> l is an in-register sum + shfl_xor(32). P round-trips per-wave LDS.
// All LDS pitches are (4k+2)-dword => b64 accesses are <=2-way conflicts.
__device__ __forceinline__ void attn3_core(
    const u16* __restrict__ Qg, int ldq,
    const u16* __restrict__ Kg, int ldk,
    const u16* __restrict__ Vtg,          // [32 d][784 k] for this (b,h)
    u16* __restrict__ Og, int ldo,
    int qt, int rowbase, int qkcol, int ocol)
{
    __shared__ u16 Qs[128][36];
    __shared__ u16 Ks[2][64][36];
    __shared__ u16 Vts[2][32][68];
    __shared__ u16 Ps[4][32][68];
    __shared__ float Ls[4][32];

    const int tid = threadIdx.x, wave = tid >> 6, lane = tid & 63;
    const int l32 = lane & 31, hi = lane >> 5;
    const int sr = tid >> 2, sc8 = (tid & 3) * 8;     // K stage: 64r x 32c
    const int vd = tid >> 3, vk8 = (tid & 7) * 8;     // V stage: 32r x 64c
    const int qr = tid >> 1, qc = (tid & 1) * 16;     // Q stage: 128r x 32c
    const float QSC = 0.25503489f;        // 32^-0.5 * log2(e)

    {   // stage Q, pre-scaled
        int qrow = qt*128 + qr;
        u8_4 a, b;
        u16x8 z8 = {0,0,0,0,0,0,0,0};
        a.v8 = z8; b.v8 = z8;
        if (qrow < 784) {
            const u16* qp = Qg + (size_t)(rowbase + qrow) * ldq + qkcol + qc;
            a.v8 = *(const u16x8*)qp;
            b.v8 = *(const u16x8*)(qp + 8);
        }
#pragma unroll
        for (int j = 0; j < 8; j++) {
            a.v8[j] = f2bf(bf2f(a.v8[j]) * QSC);
            b.v8[j] = f2bf(bf2f(b.v8[j]) * QSC);
        }
        *(u16x4*)&Qs[qr][qc]      = a.v4[0];
        *(u16x4*)&Qs[qr][qc + 4]  = a.v4[1];
        *(u16x4*)&Qs[qr][qc + 8]  = b.v4[0];
        *(u16x4*)&Qs[qr][qc + 12] = b.v4[1];
    }
    {   // stage K,V tile 0 (all rows/cols valid)
        u8_4 k, v;
        k.v8 = *(const u16x8*)(Kg + (size_t)(rowbase + sr) * ldk + qkcol + sc8);
        v.v8 = *(const u16x8*)(Vtg + (size_t)vd * 784 + vk8);
        *(u16x4*)&Ks[0][sr][sc8]     = k.v4[0];
        *(u16x4*)&Ks[0][sr][sc8 + 4] = k.v4[1];
        *(u16x4*)&Vts[0][vd][vk8]     = v.v4[0];
        *(u16x4*)&Vts[0][vd][vk8 + 4] = v.v4[1];
    }
    __syncthreads();

    bf8_4 qf0, qf1;
    qf0.h[0] = *(const u16x4*)&Qs[wave*32 + l32][hi*8];
    qf0.h[1] = *(const u16x4*)&Qs[wave*32 + l32][hi*8 + 4];
    qf1.h[0] = *(const u16x4*)&Qs[wave*32 + l32][16 + hi*8];
    qf1.h[1] = *(const u16x4*)&Qs[wave*32 + l32][16 + hi*8 + 4];

    f32x16 oacc;
#pragma unroll
    for (int i = 0; i < 16; i++) oacc[i] = 0.f;
    float lsum = 0.f;

    u16x8 kr, vr;
    for (int t = 0; t < 13; ++t) {
        const int cur = t & 1;
        if (t < 12) {   // prefetch next tile into regs
            u16x8 z8 = {0,0,0,0,0,0,0,0}; kr = z8; vr = z8;
            int krow = (t+1)*64 + sr;
            if (krow < 784)
                kr = *(const u16x8*)(Kg + (size_t)(rowbase + krow) * ldk + qkcol + sc8);
            int kc = (t+1)*64 + vk8;
            if (kc + 7 < 784)
                vr = *(const u16x8*)(Vtg + (size_t)vd * 784 + kc);
        }
        const int kvalid = (t == 12) ? 16 : 64;
        // S^T (two 32k blocks): C row = k-local, col = q = l32
#pragma unroll
        for (int kb2 = 0; kb2 < 2; kb2++) {
            f32x16 sacc;
#pragma unroll
            for (int i = 0; i < 16; i++) sacc[i] = 0.f;
            bf8_4 kf0, kf1;
            kf0.h[0] = *(const u16x4*)&Ks[cur][kb2*32 + l32][hi*8];
            kf0.h[1] = *(const u16x4*)&Ks[cur][kb2*32 + l32][hi*8 + 4];
            kf1.h[0] = *(const u16x4*)&Ks[cur][kb2*32 + l32][16 + hi*8];
            kf1.h[1] = *(const u16x4*)&Ks[cur][kb2*32 + l32][16 + hi*8 + 4];
            sacc = __builtin_amdgcn_mfma_f32_32x32x16_bf16(kf0.f, qf0.f, sacc, 0,0,0);
            sacc = __builtin_amdgcn_mfma_f32_32x32x16_bf16(kf1.f, qf1.f, sacc, 0,0,0);
#pragma unroll
            for (int g = 0; g < 4; g++) {
                int k0 = kb2*32 + 8*g + 4*hi;
                union { unsigned u[2]; u16x4 v; } pk;
                if (k0 < kvalid) {
                    float p0 = exp2f(sacc[4*g+0]);
                    float p1 = exp2f(sacc[4*g+1]);
                    float p2 = exp2f(sacc[4*g+2]);
                    float p3 = exp2f(sacc[4*g+3]);
                    lsum += (p0 + p1) + (p2 + p3);
                    pk.u[0] = cvt_pk_bf16(p0, p1);
                    pk.u[1] = cvt_pk_bf16(p2, p3);
                } else { pk.u[0] = 0; pk.u[1] = 0; }
                *(u16x4*)&Ps[wave][l32][k0] = pk.v;
            }
        }
        // PV: O[q][d] += P[q][k] V[k][d], 4 k-frags of 16
#pragma unroll
        for (int kf2 = 0; kf2 < 4; kf2++) {
            bf8_4 pf, vf;
            pf.h[0] = *(const u16x4*)&Ps[wave][l32][kf2*16 + hi*8];
            pf.h[1] = *(const u16x4*)&Ps[wave][l32][kf2*16 + hi*8 + 4];
            vf.h[0] = *(const u16x4*)&Vts[cur][l32][kf2*16 + hi*8];
            vf.h[1] = *(const u16x4*)&Vts[cur][l32][kf2*16 + hi*8 + 4];
            oacc = __builtin_amdgcn_mfma_f32_32x32x16_bf16(pf.f, vf.f, oacc, 0,0,0);
        }
        __syncthreads();
        if (t < 12) {
            u8_4 k, v; k.v8 = kr; v.v8 = vr;
            *(u16x4*)&Ks[cur^1][sr][sc8]     = k.v4[0];
            *(u16x4*)&Ks[cur^1][sr][sc8 + 4] = k.v4[1];
            *(u16x4*)&Vts[cur^1][vd][vk8]     = v.v4[0];
            *(u16x4*)&Vts[cur^1][vd][vk8 + 4] = v.v4[1];
        }
        __syncthreads();
    }
    // total l per q (lane l32 and l32+32 hold the two halves)
    float lt = lsum + __shfl_xor(lsum, 32);
    if (hi == 0) Ls[wave][l32] = lt;
    f32x4 lv[4];
#pragma unroll
    for (int g = 0; g < 4; g++) lv[g] = *(const f32x4*)&Ls[wave][8*g + 4*hi];
    // O store: reg 4g+j -> row j+8g+4hi, col d = l32
#pragma unroll
    for (int g = 0; g < 4; g++)
#pragma unroll
        for (int j = 0; j < 4; j++) {
            int row = qt*128 + wave*32 + 8*g + 4*hi + j;
            if (row < 784)
                Og[(size_t)(rowbase + row) * ldo + ocol + l32] =
                    f2bf(oacc[4*g+j] * __builtin_amdgcn_rcpf(lv[g][j]));
        }
}

// group-of-4 attention: 1792 blocks; z = inv*2 + dir (Q side = dir, K/V = dir^1)
__global__ __launch_bounds__(256) void attn_pair_kernel(
    const u16* __restrict__ projc, const u16* __restrict__ vt,
    u16* __restrict__ fusedin)
{
    int id = blockIdx.x;
    int wg = (id & 7) * 224 + (id >> 3);      // 1792/8 = 224
    int qt = wg % 7, bh = (wg / 7) & 31, z = wg / 224;
    int inv = z >> 1, dir = z & 1;
    const u16* Q  = projc + (size_t)z * 3 * MD;
    const u16* K  = projc + (size_t)(z ^ 1) * 3 * MD + 256;
    const u16* Vt = vt + (size_t)z * MD + (size_t)bh * 32 * 784;
    u16* O = fusedin + (size_t)inv * 2 * MD;
    int bb = bh >> 3, hh = bh & 7;
    attn3_core(Q, 768, K, 768, Vt, O, 512, qt, bb*784, hh*32, dir*256 + hh*32);
}

__global__ __launch_bounds__(256) void attn_mha_kernel(
    const u16* __restrict__ qkv, const u16* __restrict__ vtmha,
    u16* __restrict__ outp)
{
    int id = blockIdx.x;
    int wg = (id & 7) * 28 + (id >> 3);       // 224/8 = 28
    int qt = wg % 7, bh = wg / 7;
    int bb = bh >> 3, hh = bh & 7;
    const u16* Vt = vtmha + (size_t)bh * 32 * 784;
    attn3_core(qkv, 768, qkv + 256, 768, Vt, outp, 256, qt, bb*784, hh*32, hh*32);
}

// ---------------- LayerNorm (bf16 io): out = [prev +] os*(LN(res + tg*x)) ---
__global__ __launch_bounds__(256) void ln_kernel(
    const u16* __restrict__ x, int zx,
    const u16* __restrict__ res, int zres,
    const float* __restrict__ gamma, int i0, int i1, int i2, int i3,
    const float* __restrict__ g, const float* __restrict__ beta, int gN,
    u16* __restrict__ out, int zout,
    float outscale, int accum, int D)
{
    int z = blockIdx.y;
    int iz = (z == 0) ? i0 : (z == 1) ? i1 : (z == 2) ? i2 : i3;
    const u16* xb = x + (size_t)z * zx;
    const u16* rb = res ? res + (size_t)z * zres : (const u16*)nullptr;
    u16* ob = out + (size_t)z * zout;
    const float* gg = g + iz * gN;
    const float* bb = beta + iz * gN;
    int wave = threadIdx.x >> 6, lane = threadIdx.x & 63;
    size_t row = (size_t)blockIdx.x * 4 + wave;
    float tg = gamma ? tanhf(gamma[iz]) : 1.0f;
    const u16* xr = xb + row * D;
    const u16* rr = rb ? rb + row * D : (const u16*)nullptr;
    float vals[16];
    int nch = D >> 8;
    float s = 0.f, s2 = 0.f;
    for (int c = 0; c < nch; c++) {
        int col = c * 256 + lane * 4;
        u16x4 v = *(const u16x4*)(xr + col);
#pragma unroll
        for (int j = 0; j < 4; j++) {
            float a = tg * bf2f(v[j]);
            if (rr) a += bf2f(rr[col + j]);
            vals[c*4 + j] = a;
            s += a; s2 += a * a;
        }
    }
    for (int off = 1; off < 64; off <<= 1) {
        s  += __shfl_xor(s, off);
        s2 += __shfl_xor(s2, off);
    }
    float inv = 1.0f / D;
    float mean = s * inv;
    float var = s2 * inv - mean * mean;
    float rstd = rsqrtf(var + 1e-5f);
    for (int c = 0; c < nch; c++) {
        int col = c * 256 + lane * 4;
#pragma unroll
        for (int j = 0; j < 4; j++) {
            float o = (vals[c*4 + j] - mean) * rstd * gg[col + j] + bb[col + j];
            o *= outscale;
            if (accum) o += bf2f(ob[row*D + col + j]);
            ob[row*D + col + j] = f2bf(o);
        }
    }
}

// ---------------- layout kernels --------------------------------------------
__device__ __forceinline__ void transpose_body(const float* in, u16* out, int K, int N)
{
    __shared__ float t[32][33];
    int tx = threadIdx.x, ty = threadIdx.y;   // (32,8)
#pragma unroll
    for (int j = 0; j < 4; j++)
        t[ty + j*8][tx] = in[(size_t)(blockIdx.y*32 + ty + j*8) * N + blockIdx.x*32 + tx];
    __syncthreads();
#pragma unroll
    for (int j = 0; j < 4; j++)
        out[(size_t)(blockIdx.x*32 + ty + j*8) * K + blockIdx.y*32 + tx] =
            f2bf(t[tx][ty + j*8]);
}

__global__ __launch_bounds__(256) void transpose_w(const float* __restrict__ in,
                                                   u16* __restrict__ out, int K, int N)
{
    int z = blockIdx.z;
    transpose_body(in + (size_t)z * K * N, out + (size_t)z * K * N, K, N);
}

// proj weights into cat layout: [i][ab][768 n][256 k]
__global__ __launch_bounds__(256) void transpose_w6(
    const float* w0, const float* w1, const float* w2,
    const float* w3, const float* w4, const float* w5,
    u16* __restrict__ out)
{
    int z = blockIdx.z;           // 0..23: tsr = z/4, i = z%4
    int tsr = z >> 2, i = z & 3;
    const float* ws[6] = {w0,w1,w2,w3,w4,w5};
    int ab = (tsr >= 3) ? 1 : 0;
    u16* ob = out + (size_t)((i*2 + ab)*3 + (tsr % 3)) * 65536;
    transpose_body(ws[tsr] + (size_t)i * 65536, ob, 256, 256);
}

// transpose V (cols 512..767 of a 768-wide qkv buffer) -> [z][bh*32+d][784]
__global__ __launch_bounds__(256) void vtrans_kernel(
    const u16* __restrict__ base, int mode,
    u16* __restrict__ outbase)
{
    __shared__ u16 t[64][44];
    int z = blockIdx.z;
    size_t off = (mode ? (size_t)0 : (size_t)(z ^ 1) * 3 * MD) + 512;
    const u16* in = base + off;
    u16* out = outbase + (size_t)z * MD;
    int kt = blockIdx.x, bh = blockIdx.y;
    int bb = bh >> 3, hh = bh & 7;
    int tid = threadIdx.x;
    {
        int r = tid >> 2, c8 = (tid & 3) * 8;
        int krow = kt*64 + r;
        u16x8 u = {0,0,0,0,0,0,0,0};
        if (krow < 784)
            u = *(const u16x8*)(in + (size_t)(bb*784 + krow) * 768 + hh*32 + c8);
        *(u16x8*)&t[r][c8] = u;
    }
    __syncthreads();
    int d = tid >> 3, k8 = (tid & 7) * 8;
    if (kt*64 + k8 + 7 < 784) {
        u16x8 u;
#pragma unroll
        for (int j = 0; j < 8; j++) u[j] = t[k8 + j][d];
        *(u16x8*)&out[(size_t)(bh*32 + d) * 784 + kt*64 + k8] = u;
    }
}

// f[B,256,28,28] fp32 -> s[fi][b*784+hw][d] bf16
__global__ __launch_bounds__(256) void to_seq_kernel(
    const float* f0, const float* f1, const float* f2, const float* f3,
    u16* __restrict__ sbase)
{
    __shared__ float t[16][17];
    int z = blockIdx.z;
    int fi = z & 3, b = z >> 2;
    const float* fs[4] = {f0,f1,f2,f3};
    const float* f = fs[fi] + (size_t)b * 256 * 784;
    u16* s = sbase + (size_t)fi * MD + (size_t)b * 784 * 256;
    int tx = threadIdx.x, ty = threadIdx.y;  // (16,16)
    t[ty][tx] = f[(size_t)(blockIdx.y*16 + ty) * 784 + blockIdx.x*16 + tx];
    __syncthreads();
    s[(size_t)(blockIdx.x*16 + ty) * 256 + blockIdx.y*16 + tx] = f2bf(t[tx][ty]);
}

// y[b*784+hw][d] bf16 -> out[b][d][h][w] fp32
__global__ __launch_bounds__(256) void from_seq_kernel(const u16* __restrict__ y,
                                                       float* __restrict__ out)
{
    __shared__ float t[16][17];
    int b = blockIdx.z;
    const u16* yb = y + (size_t)b * 784 * 256;
    float* ob = out + (size_t)b * 256 * 784;
    int tx = threadIdx.x, ty = threadIdx.y;
    t[ty][tx] = bf2f(yb[(size_t)(blockIdx.x*16 + ty) * 256 + blockIdx.y*16 + tx]);
    __syncthreads();
    ob[(size_t)(blockIdx.y*16 + ty) * 784 + blockIdx.x*16 + tx] = t[tx][ty];
}

// ---------------- host orchestration ----------------------------------------
extern "C" void kernel_launch(void* const* d_in, const int* in_sizes, int n_in,
                              void* d_out, int out_size, void* d_ws, size_t ws_size,
                              hipStream_t stream)
{
    (void)in_sizes; (void)n_in; (void)out_size; (void)ws_size;
    const float* f0 = (const float*)d_in[0];
    const float* f1 = (const float*)d_in[1];
    const float* f2 = (const float*)d_in[2];
    const float* f3 = (const float*)d_in[3];
    const float* Wq_a = (const float*)d_in[4];
    const float* Wk_a = (const float*)d_in[5];
    const float* Wv_a = (const float*)d_in[6];
    const float* Wq_b = (const float*)d_in[7];
    const float* Wk_b = (const float*)d_in[8];
    const float* Wv_b = (const float*)d_in[9];
    const float* bq_a = (const float*)d_in[10];
    const float* bk_a = (const float*)d_in[11];
    const float* bv_a = (const float*)d_in[12];
    const float* bq_b = (const float*)d_in[13];
    const float* bk_b = (const float*)d_in[14];
    const float* bv_b = (const float*)d_in[15];
    const float* gamma = (const float*)d_in[16];
    const float* gamma_ffn = (const float*)d_in[17];
    const float* Wfuse = (const float*)d_in[18];
    const float* bfuse = (const float*)d_in[19];
    const float* W1 = (const float*)d_in[20];
    const float* b1 = (const float*)d_in[21];
    const float* W2 = (const float*)d_in[22];
    const float* b2 = (const float*)d_in[23];
    const float* ln1_g = (const float*)d_in[24];
    const float* ln1_b = (const float*)d_in[25];
    const float* ln2_g = (const float*)d_in[26];
    const float* ln2_b = (const float*)d_in[27];
    const float* fp_ln_g = (const float*)d_in[28];
    const float* fp_ln_b = (const float*)d_in[29];
    const float* fp_W = (const float*)d_in[30];
    const float* fp_b = (const float*)d_in[31];
    const float* ff_ln_g = (const float*)d_in[32];
    const float* ff_ln_b = (const float*)d_in[33];
    const float* ff_W = (const float*)d_in[34];
    const float* ff_b = (const float*)d_in[35];
    const float* mha_Wqkv = (const float*)d_in[36];
    const float* mha_bqkv = (const float*)d_in[37];
    const float* mha_Wo = (const float*)d_in[38];
    const float* mha_bo = (const float*)d_in[39];
    const float* norm_g = (const float*)d_in[40];
    const float* norm_b = (const float*)d_in[41];

    u16* W = (u16*)d_ws;
    u16* projWt = W;                          // 24*65536 = 1572864
    u16* fuseWt = projWt + 1572864;           // 524288
    u16* W1t    = fuseWt + 524288;            // 1048576
    u16* W2t    = W1t + 1048576;              // 1048576
    u16* fpWt   = W2t + 1048576;              // 65536
    u16* ffWt   = fpWt + 65536;               // 262144
    u16* qkvWt  = ffWt + 262144;              // 196608
    u16* WoWt   = qkvWt + 196608;             // 65536
    float* biasc = (float*)(WoWt + 65536);    // 6144 floats
    u16* act    = (u16*)(biasc + 6144);

    u16* s     = act;               // 4 MD
    u16* e     = act + 4*MD;        // 4 MD
    u16* projc = act + 8*MD;        // 24 MD
    u16* vt    = act + 32*MD;       // 8 MD
    u16* fin   = act + 40*MD;       // 8 MD   (peak: 48 MD)
    // overlays (projc/vt dead at time of use)
    u16* ffh  = projc;              // 16 MD
    u16* fb   = projc + 16*MD;      // 4 MD
    u16* xa1  = projc + 20*MD;      // 4 MD
    u16* ffb  = vt;                 // 4 MD

    // input layout + weight pre-transpose
    to_seq_kernel<<<dim3(49,16,16), dim3(16,16), 0, stream>>>(f0,f1,f2,f3, s);
    transpose_w6<<<dim3(8,8,24), dim3(32,8), 0, stream>>>(Wq_a,Wk_a,Wv_a,Wq_b,Wk_b,Wv_b, projWt);
    pack_bias_kernel<<<24, 256, 0, stream>>>(bq_a,bk_a,bv_a,bq_b,bk_b,bv_b, biasc);
    transpose_w<<<dim3(8,16,4), dim3(32,8), 0, stream>>>(Wfuse, fuseWt, 512, 256);
    transpose_w<<<dim3(32,8,4), dim3(32,8), 0, stream>>>(W1, W1t, 256, 1024);
    transpose_w<<<dim3(8,32,4), dim3(32,8), 0, stream>>>(W2, W2t, 1024, 256);
    transpose_w<<<dim3(8,8,1),  dim3(32,8), 0, stream>>>(fp_W, fpWt, 256, 256);
    transpose_w<<<dim3(8,32,1), dim3(32,8), 0, stream>>>(ff_W, ffWt, 1024, 256);
    transpose_w<<<dim3(24,8,1), dim3(32,8), 0, stream>>>(mha_Wqkv, qkvWt, 256, 768);
    transpose_w<<<dim3(8,8,1),  dim3(32,8), 0, stream>>>(mha_Wo, WoWt, 256, 256);

    // two groups of 4 independent block invocations (a-side = s[inv]):
    // A = {bi0,bi2,bi4,bi6}: i={0,0,2,1}, b={1,0,1,0}, accum=0
    // B = {bi1,bi3,bi5,bi7}: i={1,2,3,3}, b={3,2,3,2}, accum=1
    const int GI[2][4] = {{0,0,2,1},{1,2,3,3}};
    const int GB[2][4] = {{1,0,1,0},{3,2,3,2}};

    for (int g = 0; g < 2; g++) {
        int i0 = GI[g][0], i1 = GI[g][1], i2 = GI[g][2], i3 = GI[g][3];
        proj8_kernel<<<dim3(49,12,8), 256, 0, stream>>>(s,
            GB[g][0], GB[g][1], GB[g][2], GB[g][3], i0, i1, i2, i3,
            projWt, biasc, projc);
        vtrans_kernel<<<dim3(13,32,8), 256, 0, stream>>>(projc, 0, vt);
        attn_pair_kernel<<<1792, 256, 0, stream>>>(projc, vt, fin);
        gemm2_kernel<<<dim3(49,4,4), 256, 0, stream>>>(fin, 512, (int)(2*MD),
            fuseWt, 512, i0, i1, i2, i3, 131072, bfuse, 256, fb, 256, (int)MD, 0);
        ln_kernel<<<dim3(784,4), 256, 0, stream>>>(fb, (int)MD,
            s, (int)MD, gamma, i0, i1, i2, i3, ln1_g, ln1_b, 256,
            xa1, (int)MD, 1.0f, 0, 256);
        gemm2_kernel<<<dim3(49,16,4), 256, 0, stream>>>(xa1, 256, (int)MD,
            W1t, 256, i0, i1, i2, i3, 262144, b1, 1024, ffh, 1024, (int)(4*MD), 1);
        gemm2_kernel<<<dim3(49,4,4), 256, 0, stream>>>(ffh, 1024, (int)(4*MD),
            W2t, 1024, i0, i1, i2, i3, 262144, b2, 256, ffb, 256, (int)MD, 0);
        ln_kernel<<<dim3(784,4), 256, 0, stream>>>(ffb, (int)MD,
            xa1, (int)MD, gamma_ffn, i0, i1, i2, i3, ln2_g, ln2_b, 256,
            e, (int)MD, 0.5f, g, 256);
    }

    // final fuse stage (reuse dead scratch; e live until first LN done)
    u16* ln4    = act + 8*MD;        // 4 MD
    u16* allf   = act + 12*MD;       // 4 MD  [3136][1024]
    u16* ffln   = act + 16*MD;       // 4 MD
    u16* x2     = act + 20*MD;       // 1 MD
    u16* qkv    = act + 21*MD;       // 3 MD  [3136][768]
    u16* vtmha  = act + 24*MD;       // 1 MD
    u16* attn_o = act + 25*MD;       // 1 MD
    u16* ymid   = act + 26*MD;       // 1 MD
    u16* yfin   = act + 27*MD;       // 1 MD

    ln_kernel<<<dim3(784,4), 256, 0, stream>>>(e, (int)MD,
        (const u16*)nullptr, 0, (const float*)nullptr, 0,0,0,0,
        fp_ln_g, fp_ln_b, 0, ln4, (int)MD, 1.0f, 0, 256);
    gemm2_kernel<<<dim3(49,4,4), 256, 0, stream>>>(ln4, 256, (int)MD,
        fpWt, 256, 0,0,0,0, 0, fp_b, 0, allf, 1024, 256, 1);
    ln_kernel<<<dim3(784,1), 256, 0, stream>>>(allf, 0,
        (const u16*)nullptr, 0, (const float*)nullptr, 0,0,0,0,
        ff_ln_g, ff_ln_b, 0, ffln, 0, 1.0f, 0, 1024);
    gemm2_kernel<<<dim3(49,4,1), 256, 0, stream>>>(ffln, 1024, 0,
        ffWt, 1024, 0,0,0,0, 0, ff_b, 0, x2, 256, 0, 1);
    gemm2_kernel<<<dim3(49,12,1), 256, 0, stream>>>(x2, 256, 0,
        qkvWt, 256, 0,0,0,0, 0, mha_bqkv, 0, qkv, 768, 0, 0);
    vtrans_kernel<<<dim3(13,32,1), 256, 0, stream>>>(qkv, 1, vtmha);
    attn_mha_kernel<<<224, 256, 0, stream>>>(qkv, vtmha, attn_o);
    gemm2_kernel<<<dim3(49,4,1), 256, 0, stream>>>(attn_o, 256, 0,
        WoWt, 256, 0,0,0,0, 0, mha_bo, 0, ymid, 256, 0, 0);
    ln_kernel<<<dim3(784,1), 256, 0, stream>>>(ymid, 0,
        (const u16*)nullptr, 0, (const float*)nullptr, 0,0,0,0,
        norm_g, norm_b, 0, yfin, 0, 1.0f, 0, 256);
    from_seq_kernel<<<dim3(49,16,4), dim3(16,16), 0, stream>>>(yfin, (float*)d_out);
}

// Round 10
// 482.809 us; speedup vs baseline: 1.2647x; 1.0066x over previous
//
#include <hip/hip_runtime.h>

typedef unsigned short u16;
typedef __bf16 bf16x8 __attribute__((ext_vector_type(8)));
typedef float f32x4 __attribute__((ext_vector_type(4)));
typedef float f32x16 __attribute__((ext_vector_type(16)));
typedef unsigned short u16x8 __attribute__((ext_vector_type(8)));
typedef unsigned short u16x4 __attribute__((ext_vector_type(4)));

static constexpr size_t MD = 802816;   // 3136*256 elements

__device__ __forceinline__ u16 f2bf(float f) {
    __bf16 h = (__bf16)f;
    return __builtin_bit_cast(unsigned short, h);
}
__device__ __forceinline__ float bf2f(u16 u) {
    return __uint_as_float(((unsigned)u) << 16);
}
__device__ __forceinline__ float gelu_f(float x) {
    return 0.5f * x * (1.0f + erff(x * 0.70710678118654752f));
}
// pack two f32 -> two bf16 in one u32 (low = a, high = b)
__device__ __forceinline__ unsigned cvt_pk_bf16(float a, float b) {
    unsigned r;
    asm("v_cvt_pk_bf16_f32 %0, %1, %2" : "=v"(r) : "v"(a), "v"(b));
    return r;
}
union u8_4 { u16x8 v8; u16x4 v4[2]; };
union bf8_4 { bf16x8 f; u16x4 h[2]; u16x8 v8; };

// ------------- bf16 GEMM core, 64x64 tile, BK=64, swapped epilogue ----------
__device__ __forceinline__ void gemm_core(
    const u16* __restrict__ A, int lda,
    const u16* __restrict__ Bt, int K,
    const float* __restrict__ bias,
    u16* __restrict__ C, int ldc, int act)
{
    __shared__ u16 As[64][72];
    __shared__ u16 Bs[64][72];
    const int tid  = threadIdx.x;
    const int wave = tid >> 6, lane = tid & 63;
    const int wr = wave >> 1, wc = wave & 1;
    const int l16 = lane & 15, kg = lane >> 4, kb = kg * 8;
    const int m0 = blockIdx.x * 64, n0 = blockIdx.y * 64;
    const int srow = tid >> 2, scol = (tid & 3) * 16;

    f32x4 acc[2][2];   // [n-frag][m-frag]
#pragma unroll
    for (int j = 0; j < 2; j++)
#pragma unroll
        for (int i = 0; i < 2; i++) { f32x4 z = {0.f,0.f,0.f,0.f}; acc[j][i] = z; }

    const u16* ap = A + (size_t)(m0 + srow) * lda + scol;
    const u16* bp = Bt + (size_t)(n0 + srow) * K + scol;
    u16x8 ua0 = *(const u16x8*)ap;
    u16x8 ua1 = *(const u16x8*)(ap + 8);
    u16x8 ub0 = *(const u16x8*)bp;
    u16x8 ub1 = *(const u16x8*)(bp + 8);

    for (int kt = 0; kt < K; kt += 64) {
        *(u16x8*)&As[srow][scol]     = ua0;
        *(u16x8*)&As[srow][scol + 8] = ua1;
        *(u16x8*)&Bs[srow][scol]     = ub0;
        *(u16x8*)&Bs[srow][scol + 8] = ub1;
        __syncthreads();
        if (kt + 64 < K) {
            ua0 = *(const u16x8*)(ap + kt + 64);
            ua1 = *(const u16x8*)(ap + kt + 72);
            ub0 = *(const u16x8*)(bp + kt + 64);
            ub1 = *(const u16x8*)(bp + kt + 72);
        }
#pragma unroll
        for (int h = 0; h < 2; h++) {
            bf16x8 af[2], bf[2];
#pragma unroll
            for (int j = 0; j < 2; j++)
                af[j] = *(const bf16x8*)&Bs[wc*32 + j*16 + l16][h*32 + kb];
#pragma unroll
            for (int i = 0; i < 2; i++)
                bf[i] = *(const bf16x8*)&As[wr*32 + i*16 + l16][h*32 + kb];
#pragma unroll
            for (int j = 0; j < 2; j++)
#pragma unroll
                for (int i = 0; i < 2; i++)
                    acc[j][i] = __builtin_amdgcn_mfma_f32_16x16x32_bf16(
                        af[j], bf[i], acc[j][i], 0,0,0);
        }
        __syncthreads();
    }
#pragma unroll
    for (int j = 0; j < 2; j++) {
        int wcol = n0 + wc*32 + j*16 + kg*4;
        f32x4 bv = *(const f32x4*)&bias[wcol];
#pragma unroll
        for (int i = 0; i < 2; i++) {
            int row = m0 + wr*32 + i*16 + l16;
            u16x4 o;
#pragma unroll
            for (int r = 0; r < 4; r++) {
                float v = acc[j][i][r] + bv[r];
                if (act == 1) v = gelu_f(v);
                o[r] = f2bf(v);
            }
            *(u16x4*)&C[(size_t)row * ldc + wcol] = o;
        }
    }
}

// generic z-batched GEMM
__global__ __launch_bounds__(256) void gemm2_kernel(
    const u16* __restrict__ A, int lda, int zA,
    const u16* __restrict__ Bt, int K, int i0, int i1, int i2, int i3, int Bsz,
    const float* __restrict__ bias, int bN,
    u16* __restrict__ C, int ldc, int zC, int act)
{
    int z = blockIdx.z;
    int iz = (z == 0) ? i0 : (z == 1) ? i1 : (z == 2) ? i2 : i3;
    gemm_core(A + (size_t)z * zA, lda,
              Bt + (size_t)iz * Bsz, K,
              bias + (size_t)iz * bN,
              C + (size_t)z * zC, ldc, act);
}

// cat projections: z = inv*2 + ab; output [3136][768] (q|k|v) per (inv,ab)
__global__ __launch_bounds__(256) void proj8_kernel(
    const u16* __restrict__ s, int b0, int b1, int b2, int b3,
    int i0, int i1, int i2, int i3,
    const u16* __restrict__ projWt, const float* __restrict__ biasc,
    u16* __restrict__ projc)
{
    int z = blockIdx.z;
    int inv = z >> 1, ab = z & 1;
    int bi = (inv == 0) ? b0 : (inv == 1) ? b1 : (inv == 2) ? b2 : b3;
    int ii = (inv == 0) ? i0 : (inv == 1) ? i1 : (inv == 2) ? i2 : i3;
    const u16* A = s + (size_t)(ab ? bi : inv) * MD;
    int widx = ii * 2 + ab;
    gemm_core(A, 256, projWt + (size_t)widx * 768 * 256, 256,
              biasc + widx * 768,
              projc + (size_t)z * 3 * MD, 768, 0);
}

__global__ __launch_bounds__(256) void pack_bias_kernel(
    const float* b0, const float* b1, const float* b2,
    const float* b3, const float* b4, const float* b5,
    float* __restrict__ biasc)
{
    int z = blockIdx.x;
    int tsr = z >> 2, i = z & 3;
    const float* barr[6] = {b0,b1,b2,b3,b4,b5};
    int ab = (tsr >= 3) ? 1 : 0;
    biasc[(i*2 + ab)*768 + (tsr % 3)*256 + threadIdx.x] = barr[tsr][i*256 + threadIdx.x];
}

// ---------------- flash attention core, 32x32x16 MFMA, 32 q-rows/wave -------
// QBLK=128 (4 waves). S^T = mfma32(K, Q): lane holds 16 P vals for q=lane&31.
// Q fragments loaded DIRECTLY from global (each wave's rows are its own; same
// bits as the R7 LDS-staged path). No Qs LDS: 35 KB -> 4 blocks/CU.
// exp2f ONLY (libm) — __builtin_amdgcn_exp2f produced wrong results (R8/R9).
__device__ __forceinline__ void attn3_core(
    const u16* __restrict__ Qg, int ldq,
    const u16* __restrict__ Kg, int ldk,
    const u16* __restrict__ Vtg,          // [32 d][784 k] for this (b,h)
    u16* __restrict__ Og, int ldo,
    int qt, int rowbase, int qkcol, int ocol)
{
    __shared__ u16 Ks[2][64][36];
    __shared__ u16 Vts[2][32][68];
    __shared__ u16 Ps[4][32][68];
    __shared__ float Ls[4][32];

    const int tid = threadIdx.x, wave = tid >> 6, lane = tid & 63;
    const int l32 = lane & 31, hi = lane >> 5;
    const int sr = tid >> 2, sc8 = (tid & 3) * 8;     // K stage: 64r x 32c
    const int vd = tid >> 3, vk8 = (tid & 7) * 8;     // V stage: 32r x 64c
    const float QSC = 0.25503489f;        // 32^-0.5 * log2(e)

    // direct Q fragment load (pre-scaled): row = qt*128 + wave*32 + l32
    bf8_4 qf0, qf1;
    {
        int qrow = qt*128 + wave*32 + l32;
        u16x8 z8 = {0,0,0,0,0,0,0,0};
        u16x8 q0 = z8, q1 = z8;
        if (qrow < 784) {
            const u16* qp = Qg + (size_t)(rowbase + qrow) * ldq + qkcol;
            q0 = *(const u16x8*)(qp + hi*8);        // cols hi*8 .. hi*8+7
            q1 = *(const u16x8*)(qp + 16 + hi*8);   // cols 16+hi*8 ..
        }
#pragma unroll
        for (int j = 0; j < 8; j++) {
            q0[j] = f2bf(bf2f(q0[j]) * QSC);
            q1[j] = f2bf(bf2f(q1[j]) * QSC);
        }
        qf0.v8 = q0;
        qf1.v8 = q1;
    }
    {   // stage K,V tile 0 (all rows/cols valid)
        u8_4 k, v;
        k.v8 = *(const u16x8*)(Kg + (size_t)(rowbase + sr) * ldk + qkcol + sc8);
        v.v8 = *(const u16x8*)(Vtg + (size_t)vd * 784 + vk8);
        *(u16x4*)&Ks[0][sr][sc8]     = k.v4[0];
        *(u16x4*)&Ks[0][sr][sc8 + 4] = k.v4[1];
        *(u16x4*)&Vts[0][vd][vk8]     = v.v4[0];
        *(u16x4*)&Vts[0][vd][vk8 + 4] = v.v4[1];
    }
    __syncthreads();

    f32x16 oacc;
#pragma unroll
    for (int i = 0; i < 16; i++) oacc[i] = 0.f;
    float lsum = 0.f;

    u16x8 kr, vr;
    for (int t = 0; t < 13; ++t) {
        const int cur = t & 1;
        if (t < 12) {   // prefetch next tile into regs
            u16x8 z8 = {0,0,0,0,0,0,0,0}; kr = z8; vr = z8;
            int krow = (t+1)*64 + sr;
            if (krow < 784)
                kr = *(const u16x8*)(Kg + (size_t)(rowbase + krow) * ldk + qkcol + sc8);
            int kc = (t+1)*64 + vk8;
            if (kc + 7 < 784)
                vr = *(const u16x8*)(Vtg + (size_t)vd * 784 + kc);
        }
        const int kvalid = (t == 12) ? 16 : 64;
        // S^T (two 32k blocks): C row = k-local, col = q = l32
#pragma unroll
        for (int kb2 = 0; kb2 < 2; kb2++) {
            f32x16 sacc;
#pragma unroll
            for (int i = 0; i < 16; i++) sacc[i] = 0.f;
            bf8_4 kf0, kf1;
            kf0.h[0] = *(const u16x4*)&Ks[cur][kb2*32 + l32][hi*8];
            kf0.h[1] = *(const u16x4*)&Ks[cur][kb2*32 + l32][hi*8 + 4];
            kf1.h[0] = *(const u16x4*)&Ks[cur][kb2*32 + l32][16 + hi*8];
            kf1.h[1] = *(const u16x4*)&Ks[cur][kb2*32 + l32][16 + hi*8 + 4];
            sacc = __builtin_amdgcn_mfma_f32_32x32x16_bf16(kf0.f, qf0.f, sacc, 0,0,0);
            sacc = __builtin_amdgcn_mfma_f32_32x32x16_bf16(kf1.f, qf1.f, sacc, 0,0,0);
#pragma unroll
            for (int g = 0; g < 4; g++) {
                int k0 = kb2*32 + 8*g + 4*hi;
                union { unsigned u[2]; u16x4 v; } pk;
                if (k0 < kvalid) {
                    float p0 = exp2f(sacc[4*g+0]);
                    float p1 = exp2f(sacc[4*g+1]);
                    float p2 = exp2f(sacc[4*g+2]);
                    float p3 = exp2f(sacc[4*g+3]);
                    lsum += (p0 + p1) + (p2 + p3);
                    pk.u[0] = cvt_pk_bf16(p0, p1);
                    pk.u[1] = cvt_pk_bf16(p2, p3);
                } else { pk.u[0] = 0; pk.u[1] = 0; }
                *(u16x4*)&Ps[wave][l32][k0] = pk.v;
            }
        }
        // PV: O[q][d] += P[q][k] V[k][d], 4 k-frags of 16
#pragma unroll
        for (int kf2 = 0; kf2 < 4; kf2++) {
            bf8_4 pf, vf;
            pf.h[0] = *(const u16x4*)&Ps[wave][l32][kf2*16 + hi*8];
            pf.h[1] = *(const u16x4*)&Ps[wave][l32][kf2*16 + hi*8 + 4];
            vf.h[0] = *(const u16x4*)&Vts[cur][l32][kf2*16 + hi*8];
            vf.h[1] = *(const u16x4*)&Vts[cur][l32][kf2*16 + hi*8 + 4];
            oacc = __builtin_amdgcn_mfma_f32_32x32x16_bf16(pf.f, vf.f, oacc, 0,0,0);
        }
        __syncthreads();
        if (t < 12) {
            u8_4 k, v; k.v8 = kr; v.v8 = vr;
            *(u16x4*)&Ks[cur^1][sr][sc8]     = k.v4[0];
            *(u16x4*)&Ks[cur^1][sr][sc8 + 4] = k.v4[1];
            *(u16x4*)&Vts[cur^1][vd][vk8]     = v.v4[0];
            *(u16x4*)&Vts[cur^1][vd][vk8 + 4] = v.v4[1];
        }
        __syncthreads();
    }
    // total l per q (lane l32 and l32+32 hold the two halves)
    float lt = lsum + __shfl_xor(lsum, 32);
    if (hi == 0) Ls[wave][l32] = lt;
    f32x4 lv[4];
#pragma unroll
    for (int g = 0; g < 4; g++) lv[g] = *(const f32x4*)&Ls[wave][8*g + 4*hi];
    // O store: reg 4g+j -> row j+8g+4hi, col d = l32
#pragma unroll
    for (int g = 0; g < 4; g++)
#pragma unroll
        for (int j = 0; j < 4; j++) {
            int row = qt*128 + wave*32 + 8*g + 4*hi + j;
            if (row < 784)
                Og[(size_t)(rowbase + row) * ldo + ocol + l32] =
                    f2bf(oacc[4*g+j] * __builtin_amdgcn_rcpf(lv[g][j]));
        }
}

// group-of-4 attention: 1792 blocks; z = inv*2 + dir (Q side = dir, K/V = dir^1)
__global__ __launch_bounds__(256) void attn_pair_kernel(
    const u16* __restrict__ projc, const u16* __restrict__ vt,
    u16* __restrict__ fusedin)
{
    int id = blockIdx.x;
    int wg = (id & 7) * 224 + (id >> 3);      // 1792/8 = 224
    int qt = wg % 7, bh = (wg / 7) & 31, z = wg / 224;
    int inv = z >> 1, dir = z & 1;
    const u16* Q  = projc + (size_t)z * 3 * MD;
    const u16* K  = projc + (size_t)(z ^ 1) * 3 * MD + 256;
    const u16* Vt = vt + (size_t)z * MD + (size_t)bh * 32 * 784;
    u16* O = fusedin + (size_t)inv * 2 * MD;
    int bb = bh >> 3, hh = bh & 7;
    attn3_core(Q, 768, K, 768, Vt, O, 512, qt, bb*784, hh*32, dir*256 + hh*32);
}

__global__ __launch_bounds__(256) void attn_mha_kernel(
    const u16* __restrict__ qkv, const u16* __restrict__ vtmha,
    u16* __restrict__ outp)
{
    int id = blockIdx.x;
    int wg = (id & 7) * 28 + (id >> 3);       // 224/8 = 28
    int qt = wg % 7, bh = wg / 7;
    int bb = bh >> 3, hh = bh & 7;
    const u16* Vt = vtmha + (size_t)bh * 32 * 784;
    attn3_core(qkv, 768, qkv + 256, 768, Vt, outp, 256, qt, bb*784, hh*32, hh*32);
}

// ---------------- LayerNorm (bf16 io): out = [prev +] os*(LN(res + tg*x)) ---
__global__ __launch_bounds__(256) void ln_kernel(
    const u16* __restrict__ x, int zx,
    const u16* __restrict__ res, int zres,
    const float* __restrict__ gamma, int i0, int i1, int i2, int i3,
    const float* __restrict__ g, const float* __restrict__ beta, int gN,
    u16* __restrict__ out, int zout,
    float outscale, int accum, int D)
{
    int z = blockIdx.y;
    int iz = (z == 0) ? i0 : (z == 1) ? i1 : (z == 2) ? i2 : i3;
    const u16* xb = x + (size_t)z * zx;
    const u16* rb = res ? res + (size_t)z * zres : (const u16*)nullptr;
    u16* ob = out + (size_t)z * zout;
    const float* gg = g + iz * gN;
    const float* bb = beta + iz * gN;
    int wave = threadIdx.x >> 6, lane = threadIdx.x & 63;
    size_t row = (size_t)blockIdx.x * 4 + wave;
    float tg = gamma ? tanhf(gamma[iz]) : 1.0f;
    const u16* xr = xb + row * D;
    const u16* rr = rb ? rb + row * D : (const u16*)nullptr;
    float vals[16];
    int nch = D >> 8;
    float s = 0.f, s2 = 0.f;
    for (int c = 0; c < nch; c++) {
        int col = c * 256 + lane * 4;
        u16x4 v = *(const u16x4*)(xr + col);
#pragma unroll
        for (int j = 0; j < 4; j++) {
            float a = tg * bf2f(v[j]);
            if (rr) a += bf2f(rr[col + j]);
            vals[c*4 + j] = a;
            s += a; s2 += a * a;
        }
    }
    for (int off = 1; off < 64; off <<= 1) {
        s  += __shfl_xor(s, off);
        s2 += __shfl_xor(s2, off);
    }
    float inv = 1.0f / D;
    float mean = s * inv;
    float var = s2 * inv - mean * mean;
    float rstd = rsqrtf(var + 1e-5f);
    for (int c = 0; c < nch; c++) {
        int col = c * 256 + lane * 4;
#pragma unroll
        for (int j = 0; j < 4; j++) {
            float o = (vals[c*4 + j] - mean) * rstd * gg[col + j] + bb[col + j];
            o *= outscale;
            if (accum) o += bf2f(ob[row*D + col + j]);
            ob[row*D + col + j] = f2bf(o);
        }
    }
}

// ---------------- layout kernels --------------------------------------------
__device__ __forceinline__ void transpose_body(const float* in, u16* out, int K, int N)
{
    __shared__ float t[32][33];
    int tx = threadIdx.x, ty = threadIdx.y;   // (32,8)
#pragma unroll
    for (int j = 0; j < 4; j++)
        t[ty + j*8][tx] = in[(size_t)(blockIdx.y*32 + ty + j*8) * N + blockIdx.x*32 + tx];
    __syncthreads();
#pragma unroll
    for (int j = 0; j < 4; j++)
        out[(size_t)(blockIdx.x*32 + ty + j*8) * K + blockIdx.y*32 + tx] =
            f2bf(t[tx][ty + j*8]);
}

__global__ __launch_bounds__(256) void transpose_w(const float* __restrict__ in,
                                                   u16* __restrict__ out, int K, int N)
{
    int z = blockIdx.z;
    transpose_body(in + (size_t)z * K * N, out + (size_t)z * K * N, K, N);
}

// proj weights into cat layout: [i][ab][768 n][256 k]
__global__ __launch_bounds__(256) void transpose_w6(
    const float* w0, const float* w1, const float* w2,
    const float* w3, const float* w4, const float* w5,
    u16* __restrict__ out)
{
    int z = blockIdx.z;           // 0..23: tsr = z/4, i = z%4
    int tsr = z >> 2, i = z & 3;
    const float* ws[6] = {w0,w1,w2,w3,w4,w5};
    int ab = (tsr >= 3) ? 1 : 0;
    u16* ob = out + (size_t)((i*2 + ab)*3 + (tsr % 3)) * 65536;
    transpose_body(ws[tsr] + (size_t)i * 65536, ob, 256, 256);
}

// transpose V (cols 512..767 of a 768-wide qkv buffer) -> [z][bh*32+d][784]
__global__ __launch_bounds__(256) void vtrans_kernel(
    const u16* __restrict__ base, int mode,
    u16* __restrict__ outbase)
{
    __shared__ u16 t[64][44];
    int z = blockIdx.z;
    size_t off = (mode ? (size_t)0 : (size_t)(z ^ 1) * 3 * MD) + 512;
    const u16* in = base + off;
    u16* out = outbase + (size_t)z * MD;
    int kt = blockIdx.x, bh = blockIdx.y;
    int bb = bh >> 3, hh = bh & 7;
    int tid = threadIdx.x;
    {
        int r = tid >> 2, c8 = (tid & 3) * 8;
        int krow = kt*64 + r;
        u16x8 u = {0,0,0,0,0,0,0,0};
        if (krow < 784)
            u = *(const u16x8*)(in + (size_t)(bb*784 + krow) * 768 + hh*32 + c8);
        *(u16x8*)&t[r][c8] = u;
    }
    __syncthreads();
    int d = tid >> 3, k8 = (tid & 7) * 8;
    if (kt*64 + k8 + 7 < 784) {
        u16x8 u;
#pragma unroll
        for (int j = 0; j < 8; j++) u[j] = t[k8 + j][d];
        *(u16x8*)&out[(size_t)(bh*32 + d) * 784 + kt*64 + k8] = u;
    }
}

// f[B,256,28,28] fp32 -> s[fi][b*784+hw][d] bf16
__global__ __launch_bounds__(256) void to_seq_kernel(
    const float* f0, const float* f1, const float* f2, const float* f3,
    u16* __restrict__ sbase)
{
    __shared__ float t[16][17];
    int z = blockIdx.z;
    int fi = z & 3, b = z >> 2;
    const float* fs[4] = {f0,f1,f2,f3};
    const float* f = fs[fi] + (size_t)b * 256 * 784;
    u16* s = sbase + (size_t)fi * MD + (size_t)b * 784 * 256;
    int tx = threadIdx.x, ty = threadIdx.y;  // (16,16)
    t[ty][tx] = f[(size_t)(blockIdx.y*16 + ty) * 784 + blockIdx.x*16 + tx];
    __syncthreads();
    s[(size_t)(blockIdx.x*16 + ty) * 256 + blockIdx.y*16 + tx] = f2bf(t[tx][ty]);
}

// y[b*784+hw][d] bf16 -> out[b][d][h][w] fp32
__global__ __launch_bounds__(256) void from_seq_kernel(const u16* __restrict__ y,
                                                       float* __restrict__ out)
{
    __shared__ float t[16][17];
    int b = blockIdx.z;
    const u16* yb = y + (size_t)b * 784 * 256;
    float* ob = out + (size_t)b * 256 * 784;
    int tx = threadIdx.x, ty = threadIdx.y;
    t[ty][tx] = bf2f(yb[(size_t)(blockIdx.x*16 + ty) * 256 + blockIdx.y*16 + tx]);
    __syncthreads();
    ob[(size_t)(blockIdx.y*16 + ty) * 784 + blockIdx.x*16 + tx] = t[tx][ty];
}

// ---------------- host orchestration ----------------------------------------
extern "C" void kernel_launch(void* const* d_in, const int* in_sizes, int n_in,
                              void* d_out, int out_size, void* d_ws, size_t ws_size,
                              hipStream_t stream)
{
    (void)in_sizes; (void)n_in; (void)out_size; (void)ws_size;
    const float* f0 = (const float*)d_in[0];
    const float* f1 = (const float*)d_in[1];
    const float* f2 = (const float*)d_in[2];
    const float* f3 = (const float*)d_in[3];
    const float* Wq_a = (const float*)d_in[4];
    const float* Wk_a = (const float*)d_in[5];
    const float* Wv_a = (const float*)d_in[6];
    const float* Wq_b = (const float*)d_in[7];
    const float* Wk_b = (const float*)d_in[8];
    const float* Wv_b = (const float*)d_in[9];
    const float* bq_a = (const float*)d_in[10];
    const float* bk_a = (const float*)d_in[11];
    const float* bv_a = (const float*)d_in[12];
    const float* bq_b = (const float*)d_in[13];
    const float* bk_b = (const float*)d_in[14];
    const float* bv_b = (const float*)d_in[15];
    const float* gamma = (const float*)d_in[16];
    const float* gamma_ffn = (const float*)d_in[17];
    const float* Wfuse = (const float*)d_in[18];
    const float* bfuse = (const float*)d_in[19];
    const float* W1 = (const float*)d_in[20];
    const float* b1 = (const float*)d_in[21];
    const float* W2 = (const float*)d_in[22];
    const float* b2 = (const float*)d_in[23];
    const float* ln1_g = (const float*)d_in[24];
    const float* ln1_b = (const float*)d_in[25];
    const float* ln2_g = (const float*)d_in[26];
    const float* ln2_b = (const float*)d_in[27];
    const float* fp_ln_g = (const float*)d_in[28];
    const float* fp_ln_b = (const float*)d_in[29];
    const float* fp_W = (const float*)d_in[30];
    const float* fp_b = (const float*)d_in[31];
    const float* ff_ln_g = (const float*)d_in[32];
    const float* ff_ln_b = (const float*)d_in[33];
    const float* ff_W = (const float*)d_in[34];
    const float* ff_b = (const float*)d_in[35];
    const float* mha_Wqkv = (const float*)d_in[36];
    const float* mha_bqkv = (const float*)d_in[37];
    const float* mha_Wo = (const float*)d_in[38];
    const float* mha_bo = (const float*)d_in[39];
    const float* norm_g = (const float*)d_in[40];
    const float* norm_b = (const float*)d_in[41];

    u16* W = (u16*)d_ws;
    u16* projWt = W;                          // 24*65536 = 1572864
    u16* fuseWt = projWt + 1572864;           // 524288
    u16* W1t    = fuseWt + 524288;            // 1048576
    u16* W2t    = W1t + 1048576;              // 1048576
    u16* fpWt   = W2t + 1048576;              // 65536
    u16* ffWt   = fpWt + 65536;               // 262144
    u16* qkvWt  = ffWt + 262144;              // 196608
    u16* WoWt   = qkvWt + 196608;             // 65536
    float* biasc = (float*)(WoWt + 65536);    // 6144 floats
    u16* act    = (u16*)(biasc + 6144);

    u16* s     = act;               // 4 MD
    u16* e     = act + 4*MD;        // 4 MD
    u16* projc = act + 8*MD;        // 24 MD
    u16* vt    = act + 32*MD;       // 8 MD
    u16* fin   = act + 40*MD;       // 8 MD   (peak: 48 MD)
    // overlays (projc/vt dead at time of use)
    u16* ffh  = projc;              // 16 MD
    u16* fb   = projc + 16*MD;      // 4 MD
    u16* xa1  = projc + 20*MD;      // 4 MD
    u16* ffb  = vt;                 // 4 MD

    // input layout + weight pre-transpose
    to_seq_kernel<<<dim3(49,16,16), dim3(16,16), 0, stream>>>(f0,f1,f2,f3, s);
    transpose_w6<<<dim3(8,8,24), dim3(32,8), 0, stream>>>(Wq_a,Wk_a,Wv_a,Wq_b,Wk_b,Wv_b, projWt);
    pack_bias_kernel<<<24, 256, 0, stream>>>(bq_a,bk_a,bv_a,bq_b,bk_b,bv_b, biasc);
    transpose_w<<<dim3(8,16,4), dim3(32,8), 0, stream>>>(Wfuse, fuseWt, 512, 256);
    transpose_w<<<dim3(32,8,4), dim3(32,8), 0, stream>>>(W1, W1t, 256, 1024);
    transpose_w<<<dim3(8,32,4), dim3(32,8), 0, stream>>>(W2, W2t, 1024, 256);
    transpose_w<<<dim3(8,8,1),  dim3(32,8), 0, stream>>>(fp_W, fpWt, 256, 256);
    transpose_w<<<dim3(8,32,1), dim3(32,8), 0, stream>>>(ff_W, ffWt, 1024, 256);
    transpose_w<<<dim3(24,8,1), dim3(32,8), 0, stream>>>(mha_Wqkv, qkvWt, 256, 768);
    transpose_w<<<dim3(8,8,1),  dim3(32,8), 0, stream>>>(mha_Wo, WoWt, 256, 256);

    // two groups of 4 independent block invocations (a-side = s[inv]):
    // A = {bi0,bi2,bi4,bi6}: i={0,0,2,1}, b={1,0,1,0}, accum=0
    // B = {bi1,bi3,bi5,bi7}: i={1,2,3,3}, b={3,2,3,2}, accum=1
    const int GI[2][4] = {{0,0,2,1},{1,2,3,3}};
    const int GB[2][4] = {{1,0,1,0},{3,2,3,2}};

    for (int g = 0; g < 2; g++) {
        int i0 = GI[g][0], i1 = GI[g][1], i2 = GI[g][2], i3 = GI[g][3];
        proj8_kernel<<<dim3(49,12,8), 256, 0, stream>>>(s,
            GB[g][0], GB[g][1], GB[g][2], GB[g][3], i0, i1, i2, i3,
            projWt, biasc, projc);
        vtrans_kernel<<<dim3(13,32,8), 256, 0, stream>>>(projc, 0, vt);
        attn_pair_kernel<<<1792, 256, 0, stream>>>(projc, vt, fin);
        gemm2_kernel<<<dim3(49,4,4), 256, 0, stream>>>(fin, 512, (int)(2*MD),
            fuseWt, 512, i0, i1, i2, i3, 131072, bfuse, 256, fb, 256, (int)MD, 0);
        ln_kernel<<<dim3(784,4), 256, 0, stream>>>(fb, (int)MD,
            s, (int)MD, gamma, i0, i1, i2, i3, ln1_g, ln1_b, 256,
            xa1, (int)MD, 1.0f, 0, 256);
        gemm2_kernel<<<dim3(49,16,4), 256, 0, stream>>>(xa1, 256, (int)MD,
            W1t, 256, i0, i1, i2, i3, 262144, b1, 1024, ffh, 1024, (int)(4*MD), 1);
        gemm2_kernel<<<dim3(49,4,4), 256, 0, stream>>>(ffh, 1024, (int)(4*MD),
            W2t, 1024, i0, i1, i2, i3, 262144, b2, 256, ffb, 256, (int)MD, 0);
        ln_kernel<<<dim3(784,4), 256, 0, stream>>>(ffb, (int)MD,
            xa1, (int)MD, gamma_ffn, i0, i1, i2, i3, ln2_g, ln2_b, 256,
            e, (int)MD, 0.5f, g, 256);
    }

    // final fuse stage (reuse dead scratch; e live until first LN done)
    u16* ln4    = act + 8*MD;        // 4 MD
    u16* allf   = act + 12*MD;       // 4 MD  [3136][1024]
    u16* ffln   = act + 16*MD;       // 4 MD
    u16* x2     = act + 20*MD;       // 1 MD
    u16* qkv    = act + 21*MD;       // 3 MD  [3136][768]
    u16* vtmha  = act + 24*MD;       // 1 MD
    u16* attn_o = act + 25*MD;       // 1 MD
    u16* ymid   = act + 26*MD;       // 1 MD
    u16* yfin   = act + 27*MD;       // 1 MD

    ln_kernel<<<dim3(784,4), 256, 0, stream>>>(e, (int)MD,
        (const u16*)nullptr, 0, (const float*)nullptr, 0,0,0,0,
        fp_ln_g, fp_ln_b, 0, ln4, (int)MD, 1.0f, 0, 256);
    gemm2_kernel<<<dim3(49,4,4), 256, 0, stream>>>(ln4, 256, (int)MD,
        fpWt, 256, 0,0,0,0, 0, fp_b, 0, allf, 1024, 256, 1);
    ln_kernel<<<dim3(784,1), 256, 0, stream>>>(allf, 0,
        (const u16*)nullptr, 0, (const float*)nullptr, 0,0,0,0,
        ff_ln_g, ff_ln_b, 0, ffln, 0, 1.0f, 0, 1024);
    gemm2_kernel<<<dim3(49,4,1), 256, 0, stream>>>(ffln, 1024, 0,
        ffWt, 1024, 0,0,0,0, 0, ff_b, 0, x2, 256, 0, 1);
    gemm2_kernel<<<dim3(49,12,1), 256, 0, stream>>>(x2, 256, 0,
        qkvWt, 256, 0,0,0,0, 0, mha_bqkv, 0, qkv, 768, 0, 0);
    vtrans_kernel<<<dim3(13,32,1), 256, 0, stream>>>(qkv, 1, vtmha);
    attn_mha_kernel<<<224, 256, 0, stream>>>(qkv, vtmha, attn_o);
    gemm2_kernel<<<dim3(49,4,1), 256, 0, stream>>>(attn_o, 256, 0,
        WoWt, 256, 0,0,0,0, 0, mha_bo, 0, ymid, 256, 0, 0);
    ln_kernel<<<dim3(784,1), 256, 0, stream>>>(ymid, 0,
        (const u16*)nullptr, 0, (const float*)nullptr, 0,0,0,0,
        norm_g, norm_b, 0, yfin, 0, 1.0f, 0, 256);
    from_seq_kernel<<<dim3(49,16,4), dim3(16,16), 0, stream>>>(yfin, (float*)d_out);
}

// Round 11
// 448.885 us; speedup vs baseline: 1.3603x; 1.0756x over previous
//
#include <hip/hip_runtime.h>

typedef unsigned short u16;
typedef __bf16 bf16x8 __attribute__((ext_vector_type(8)));
typedef float f32x4 __attribute__((ext_vector_type(4)));
typedef float f32x16 __attribute__((ext_vector_type(16)));
typedef unsigned short u16x8 __attribute__((ext_vector_type(8)));
typedef unsigned short u16x4 __attribute__((ext_vector_type(4)));

static constexpr size_t MD = 802816;   // 3136*256 elements

__device__ __forceinline__ u16 f2bf(float f) {
    __bf16 h = (__bf16)f;
    return __builtin_bit_cast(unsigned short, h);
}
__device__ __forceinline__ float bf2f(u16 u) {
    return __uint_as_float(((unsigned)u) << 16);
}
__device__ __forceinline__ float gelu_f(float x) {
    return 0.5f * x * (1.0f + erff(x * 0.70710678118654752f));
}
// pack two f32 -> two bf16 in one u32 (low = a, high = b)
__device__ __forceinline__ unsigned cvt_pk_bf16(float a, float b) {
    unsigned r;
    asm("v_cvt_pk_bf16_f32 %0, %1, %2" : "=v"(r) : "v"(a), "v"(b));
    return r;
}
// raw 2^x via the ISA instruction (ISA ref: v_exp_f32 -> D = 2^S0).
// NOTE: __builtin_amdgcn_exp2f gave WRONG results (R8/R9 — appears to be e^x);
// libm exp2f is correct but multi-op. Inline asm pins the exact instruction.
__device__ __forceinline__ float exp2_hw(float x) {
    float r;
    asm("v_exp_f32 %0, %1" : "=v"(r) : "v"(x));
    return r;
}
union u8_4 { u16x8 v8; u16x4 v4[2]; };
union bf8_4 { bf16x8 f; u16x4 h[2]; u16x8 v8; };

// ------------- bf16 GEMM core, 64x64 tile, BK=64, swapped epilogue ----------
__device__ __forceinline__ void gemm_core(
    const u16* __restrict__ A, int lda,
    const u16* __restrict__ Bt, int K,
    const float* __restrict__ bias,
    u16* __restrict__ C, int ldc, int act)
{
    __shared__ u16 As[64][72];
    __shared__ u16 Bs[64][72];
    const int tid  = threadIdx.x;
    const int wave = tid >> 6, lane = tid & 63;
    const int wr = wave >> 1, wc = wave & 1;
    const int l16 = lane & 15, kg = lane >> 4, kb = kg * 8;
    const int m0 = blockIdx.x * 64, n0 = blockIdx.y * 64;
    const int srow = tid >> 2, scol = (tid & 3) * 16;

    f32x4 acc[2][2];   // [n-frag][m-frag]
#pragma unroll
    for (int j = 0; j < 2; j++)
#pragma unroll
        for (int i = 0; i < 2; i++) { f32x4 z = {0.f,0.f,0.f,0.f}; acc[j][i] = z; }

    const u16* ap = A + (size_t)(m0 + srow) * lda + scol;
    const u16* bp = Bt + (size_t)(n0 + srow) * K + scol;
    u16x8 ua0 = *(const u16x8*)ap;
    u16x8 ua1 = *(const u16x8*)(ap + 8);
    u16x8 ub0 = *(const u16x8*)bp;
    u16x8 ub1 = *(const u16x8*)(bp + 8);

    for (int kt = 0; kt < K; kt += 64) {
        *(u16x8*)&As[srow][scol]     = ua0;
        *(u16x8*)&As[srow][scol + 8] = ua1;
        *(u16x8*)&Bs[srow][scol]     = ub0;
        *(u16x8*)&Bs[srow][scol + 8] = ub1;
        __syncthreads();
        if (kt + 64 < K) {
            ua0 = *(const u16x8*)(ap + kt + 64);
            ua1 = *(const u16x8*)(ap + kt + 72);
            ub0 = *(const u16x8*)(bp + kt + 64);
            ub1 = *(const u16x8*)(bp + kt + 72);
        }
#pragma unroll
        for (int h = 0; h < 2; h++) {
            bf16x8 af[2], bf[2];
#pragma unroll
            for (int j = 0; j < 2; j++)
                af[j] = *(const bf16x8*)&Bs[wc*32 + j*16 + l16][h*32 + kb];
#pragma unroll
            for (int i = 0; i < 2; i++)
                bf[i] = *(const bf16x8*)&As[wr*32 + i*16 + l16][h*32 + kb];
#pragma unroll
            for (int j = 0; j < 2; j++)
#pragma unroll
                for (int i = 0; i < 2; i++)
                    acc[j][i] = __builtin_amdgcn_mfma_f32_16x16x32_bf16(
                        af[j], bf[i], acc[j][i], 0,0,0);
        }
        __syncthreads();
    }
#pragma unroll
    for (int j = 0; j < 2; j++) {
        int wcol = n0 + wc*32 + j*16 + kg*4;
        f32x4 bv = *(const f32x4*)&bias[wcol];
#pragma unroll
        for (int i = 0; i < 2; i++) {
            int row = m0 + wr*32 + i*16 + l16;
            u16x4 o;
#pragma unroll
            for (int r = 0; r < 4; r++) {
                float v = acc[j][i][r] + bv[r];
                if (act == 1) v = gelu_f(v);
                o[r] = f2bf(v);
            }
            *(u16x4*)&C[(size_t)row * ldc + wcol] = o;
        }
    }
}

// generic z-batched GEMM
__global__ __launch_bounds__(256) void gemm2_kernel(
    const u16* __restrict__ A, int lda, int zA,
    const u16* __restrict__ Bt, int K, int i0, int i1, int i2, int i3, int Bsz,
    const float* __restrict__ bias, int bN,
    u16* __restrict__ C, int ldc, int zC, int act)
{
    int z = blockIdx.z;
    int iz = (z == 0) ? i0 : (z == 1) ? i1 : (z == 2) ? i2 : i3;
    gemm_core(A + (size_t)z * zA, lda,
              Bt + (size_t)iz * Bsz, K,
              bias + (size_t)iz * bN,
              C + (size_t)z * zC, ldc, act);
}

// cat projections: z = inv*2 + ab; output [3136][768] (q|k|v) per (inv,ab)
__global__ __launch_bounds__(256) void proj8_kernel(
    const u16* __restrict__ s, int b0, int b1, int b2, int b3,
    int i0, int i1, int i2, int i3,
    const u16* __restrict__ projWt, const float* __restrict__ biasc,
    u16* __restrict__ projc)
{
    int z = blockIdx.z;
    int inv = z >> 1, ab = z & 1;
    int bi = (inv == 0) ? b0 : (inv == 1) ? b1 : (inv == 2) ? b2 : b3;
    int ii = (inv == 0) ? i0 : (inv == 1) ? i1 : (inv == 2) ? i2 : i3;
    const u16* A = s + (size_t)(ab ? bi : inv) * MD;
    int widx = ii * 2 + ab;
    gemm_core(A, 256, projWt + (size_t)widx * 768 * 256, 256,
              biasc + widx * 768,
              projc + (size_t)z * 3 * MD, 768, 0);
}

__global__ __launch_bounds__(256) void pack_bias_kernel(
    const float* b0, const float* b1, const float* b2,
    const float* b3, const float* b4, const float* b5,
    float* __restrict__ biasc)
{
    int z = blockIdx.x;
    int tsr = z >> 2, i = z & 3;
    const float* barr[6] = {b0,b1,b2,b3,b4,b5};
    int ab = (tsr >= 3) ? 1 : 0;
    biasc[(i*2 + ab)*768 + (tsr % 3)*256 + threadIdx.x] = barr[tsr][i*256 + threadIdx.x];
}

// ---------------- flash attention core, 32x32x16 MFMA, 32 q-rows/wave -------
// QBLK=128 (4 waves). S^T = mfma32(K, Q): lane holds 16 P vals for q=lane&31.
// Q fragments loaded DIRECTLY from global. No Qs LDS: 35 KB -> 4 blocks/CU.
// exp via inline-asm v_exp_f32 (2^x per ISA ref); NEVER __builtin_amdgcn_exp2f.
__device__ __forceinline__ void attn3_core(
    const u16* __restrict__ Qg, int ldq,
    const u16* __restrict__ Kg, int ldk,
    const u16* __restrict__ Vtg,          // [32 d][784 k] for this (b,h)
    u16* __restrict__ Og, int ldo,
    int qt, int rowbase, int qkcol, int ocol)
{
    __shared__ u16 Ks[2][64][36];
    __shared__ u16 Vts[2][32][68];
    __shared__ u16 Ps[4][32][68];
    __shared__ float Ls[4][32];

    const int tid = threadIdx.x, wave = tid >> 6, lane = tid & 63;
    const int l32 = lane & 31, hi = lane >> 5;
    const int sr = tid >> 2, sc8 = (tid & 3) * 8;     // K stage: 64r x 32c
    const int vd = tid >> 3, vk8 = (tid & 7) * 8;     // V stage: 32r x 64c
    const float QSC = 0.25503489f;        // 32^-0.5 * log2(e)

    // direct Q fragment load (pre-scaled): row = qt*128 + wave*32 + l32
    bf8_4 qf0, qf1;
    {
        int qrow = qt*128 + wave*32 + l32;
        u16x8 z8 = {0,0,0,0,0,0,0,0};
        u16x8 q0 = z8, q1 = z8;
        if (qrow < 784) {
            const u16* qp = Qg + (size_t)(rowbase + qrow) * ldq + qkcol;
            q0 = *(const u16x8*)(qp + hi*8);        // cols hi*8 .. hi*8+7
            q1 = *(const u16x8*)(qp + 16 + hi*8);   // cols 16+hi*8 ..
        }
#pragma unroll
        for (int j = 0; j < 8; j++) {
            q0[j] = f2bf(bf2f(q0[j]) * QSC);
            q1[j] = f2bf(bf2f(q1[j]) * QSC);
        }
        qf0.v8 = q0;
        qf1.v8 = q1;
    }
    {   // stage K,V tile 0 (all rows/cols valid)
        u8_4 k, v;
        k.v8 = *(const u16x8*)(Kg + (size_t)(rowbase + sr) * ldk + qkcol + sc8);
        v.v8 = *(const u16x8*)(Vtg + (size_t)vd * 784 + vk8);
        *(u16x4*)&Ks[0][sr][sc8]     = k.v4[0];
        *(u16x4*)&Ks[0][sr][sc8 + 4] = k.v4[1];
        *(u16x4*)&Vts[0][vd][vk8]     = v.v4[0];
        *(u16x4*)&Vts[0][vd][vk8 + 4] = v.v4[1];
    }
    __syncthreads();

    f32x16 oacc;
#pragma unroll
    for (int i = 0; i < 16; i++) oacc[i] = 0.f;
    float lsum = 0.f;

    u16x8 kr, vr;
    for (int t = 0; t < 13; ++t) {
        const int cur = t & 1;
        if (t < 12) {   // prefetch next tile into regs
            u16x8 z8 = {0,0,0,0,0,0,0,0}; kr = z8; vr = z8;
            int krow = (t+1)*64 + sr;
            if (krow < 784)
                kr = *(const u16x8*)(Kg + (size_t)(rowbase + krow) * ldk + qkcol + sc8);
            int kc = (t+1)*64 + vk8;
            if (kc + 7 < 784)
                vr = *(const u16x8*)(Vtg + (size_t)vd * 784 + kc);
        }
        const int kvalid = (t == 12) ? 16 : 64;
        // S^T (two 32k blocks): C row = k-local, col = q = l32
#pragma unroll
        for (int kb2 = 0; kb2 < 2; kb2++) {
            f32x16 sacc;
#pragma unroll
            for (int i = 0; i < 16; i++) sacc[i] = 0.f;
            bf8_4 kf0, kf1;
            kf0.h[0] = *(const u16x4*)&Ks[cur][kb2*32 + l32][hi*8];
            kf0.h[1] = *(const u16x4*)&Ks[cur][kb2*32 + l32][hi*8 + 4];
            kf1.h[0] = *(const u16x4*)&Ks[cur][kb2*32 + l32][16 + hi*8];
            kf1.h[1] = *(const u16x4*)&Ks[cur][kb2*32 + l32][16 + hi*8 + 4];
            sacc = __builtin_amdgcn_mfma_f32_32x32x16_bf16(kf0.f, qf0.f, sacc, 0,0,0);
            sacc = __builtin_amdgcn_mfma_f32_32x32x16_bf16(kf1.f, qf1.f, sacc, 0,0,0);
#pragma unroll
            for (int g = 0; g < 4; g++) {
                int k0 = kb2*32 + 8*g + 4*hi;
                union { unsigned u[2]; u16x4 v; } pk;
                if (k0 < kvalid) {
                    float p0 = exp2_hw(sacc[4*g+0]);
                    float p1 = exp2_hw(sacc[4*g+1]);
                    float p2 = exp2_hw(sacc[4*g+2]);
                    float p3 = exp2_hw(sacc[4*g+3]);
                    lsum += (p0 + p1) + (p2 + p3);
                    pk.u[0] = cvt_pk_bf16(p0, p1);
                    pk.u[1] = cvt_pk_bf16(p2, p3);
                } else { pk.u[0] = 0; pk.u[1] = 0; }
                *(u16x4*)&Ps[wave][l32][k0] = pk.v;
            }
        }
        // PV: O[q][d] += P[q][k] V[k][d], 4 k-frags of 16
#pragma unroll
        for (int kf2 = 0; kf2 < 4; kf2++) {
            bf8_4 pf, vf;
            pf.h[0] = *(const u16x4*)&Ps[wave][l32][kf2*16 + hi*8];
            pf.h[1] = *(const u16x4*)&Ps[wave][l32][kf2*16 + hi*8 + 4];
            vf.h[0] = *(const u16x4*)&Vts[cur][l32][kf2*16 + hi*8];
            vf.h[1] = *(const u16x4*)&Vts[cur][l32][kf2*16 + hi*8 + 4];
            oacc = __builtin_amdgcn_mfma_f32_32x32x16_bf16(pf.f, vf.f, oacc, 0,0,0);
        }
        __syncthreads();
        if (t < 12) {
            u8_4 k, v; k.v8 = kr; v.v8 = vr;
            *(u16x4*)&Ks[cur^1][sr][sc8]     = k.v4[0];
            *(u16x4*)&Ks[cur^1][sr][sc8 + 4] = k.v4[1];
            *(u16x4*)&Vts[cur^1][vd][vk8]     = v.v4[0];
            *(u16x4*)&Vts[cur^1][vd][vk8 + 4] = v.v4[1];
        }
        __syncthreads();
    }
    // total l per q (lane l32 and l32+32 hold the two halves)
    float lt = lsum + __shfl_xor(lsum, 32);
    if (hi == 0) Ls[wave][l32] = lt;
    f32x4 lv[4];
#pragma unroll
    for (int g = 0; g < 4; g++) lv[g] = *(const f32x4*)&Ls[wave][8*g + 4*hi];
    // O store: reg 4g+j -> row j+8g+4hi, col d = l32
#pragma unroll
    for (int g = 0; g < 4; g++)
#pragma unroll
        for (int j = 0; j < 4; j++) {
            int row = qt*128 + wave*32 + 8*g + 4*hi + j;
            if (row < 784)
                Og[(size_t)(rowbase + row) * ldo + ocol + l32] =
                    f2bf(oacc[4*g+j] * __builtin_amdgcn_rcpf(lv[g][j]));
        }
}

// group-of-4 attention: 1792 blocks; z = inv*2 + dir (Q side = dir, K/V = dir^1)
__global__ __launch_bounds__(256) void attn_pair_kernel(
    const u16* __restrict__ projc, const u16* __restrict__ vt,
    u16* __restrict__ fusedin)
{
    int id = blockIdx.x;
    int wg = (id & 7) * 224 + (id >> 3);      // 1792/8 = 224
    int qt = wg % 7, bh = (wg / 7) & 31, z = wg / 224;
    int inv = z >> 1, dir = z & 1;
    const u16* Q  = projc + (size_t)z * 3 * MD;
    const u16* K  = projc + (size_t)(z ^ 1) * 3 * MD + 256;
    const u16* Vt = vt + (size_t)z * MD + (size_t)bh * 32 * 784;
    u16* O = fusedin + (size_t)inv * 2 * MD;
    int bb = bh >> 3, hh = bh & 7;
    attn3_core(Q, 768, K, 768, Vt, O, 512, qt, bb*784, hh*32, dir*256 + hh*32);
}

__global__ __launch_bounds__(256) void attn_mha_kernel(
    const u16* __restrict__ qkv, const u16* __restrict__ vtmha,
    u16* __restrict__ outp)
{
    int id = blockIdx.x;
    int wg = (id & 7) * 28 + (id >> 3);       // 224/8 = 28
    int qt = wg % 7, bh = wg / 7;
    int bb = bh >> 3, hh = bh & 7;
    const u16* Vt = vtmha + (size_t)bh * 32 * 784;
    attn3_core(qkv, 768, qkv + 256, 768, Vt, outp, 256, qt, bb*784, hh*32, hh*32);
}

// ---------------- LayerNorm (bf16 io): out = [prev +] os*(LN(res + tg*x)) ---
__global__ __launch_bounds__(256) void ln_kernel(
    const u16* __restrict__ x, int zx,
    const u16* __restrict__ res, int zres,
    const float* __restrict__ gamma, int i0, int i1, int i2, int i3,
    const float* __restrict__ g, const float* __restrict__ beta, int gN,
    u16* __restrict__ out, int zout,
    float outscale, int accum, int D)
{
    int z = blockIdx.y;
    int iz = (z == 0) ? i0 : (z == 1) ? i1 : (z == 2) ? i2 : i3;
    const u16* xb = x + (size_t)z * zx;
    const u16* rb = res ? res + (size_t)z * zres : (const u16*)nullptr;
    u16* ob = out + (size_t)z * zout;
    const float* gg = g + iz * gN;
    const float* bb = beta + iz * gN;
    int wave = threadIdx.x >> 6, lane = threadIdx.x & 63;
    size_t row = (size_t)blockIdx.x * 4 + wave;
    float tg = gamma ? tanhf(gamma[iz]) : 1.0f;
    const u16* xr = xb + row * D;
    const u16* rr = rb ? rb + row * D : (const u16*)nullptr;
    float vals[16];
    int nch = D >> 8;
    float s = 0.f, s2 = 0.f;
    for (int c = 0; c < nch; c++) {
        int col = c * 256 + lane * 4;
        u16x4 v = *(const u16x4*)(xr + col);
#pragma unroll
        for (int j = 0; j < 4; j++) {
            float a = tg * bf2f(v[j]);
            if (rr) a += bf2f(rr[col + j]);
            vals[c*4 + j] = a;
            s += a; s2 += a * a;
        }
    }
    for (int off = 1; off < 64; off <<= 1) {
        s  += __shfl_xor(s, off);
        s2 += __shfl_xor(s2, off);
    }
    float inv = 1.0f / D;
    float mean = s * inv;
    float var = s2 * inv - mean * mean;
    float rstd = rsqrtf(var + 1e-5f);
    for (int c = 0; c < nch; c++) {
        int col = c * 256 + lane * 4;
#pragma unroll
        for (int j = 0; j < 4; j++) {
            float o = (vals[c*4 + j] - mean) * rstd * gg[col + j] + bb[col + j];
            o *= outscale;
            if (accum) o += bf2f(ob[row*D + col + j]);
            ob[row*D + col + j] = f2bf(o);
        }
    }
}

// ---------------- layout kernels --------------------------------------------
__device__ __forceinline__ void transpose_body(const float* in, u16* out, int K, int N)
{
    __shared__ float t[32][33];
    int tx = threadIdx.x, ty = threadIdx.y;   // (32,8)
#pragma unroll
    for (int j = 0; j < 4; j++)
        t[ty + j*8][tx] = in[(size_t)(blockIdx.y*32 + ty + j*8) * N + blockIdx.x*32 + tx];
    __syncthreads();
#pragma unroll
    for (int j = 0; j < 4; j++)
        out[(size_t)(blockIdx.x*32 + ty + j*8) * K + blockIdx.y*32 + tx] =
            f2bf(t[tx][ty + j*8]);
}

__global__ __launch_bounds__(256) void transpose_w(const float* __restrict__ in,
                                                   u16* __restrict__ out, int K, int N)
{
    int z = blockIdx.z;
    transpose_body(in + (size_t)z * K * N, out + (size_t)z * K * N, K, N);
}

// proj weights into cat layout: [i][ab][768 n][256 k]
__global__ __launch_bounds__(256) void transpose_w6(
    const float* w0, const float* w1, const float* w2,
    const float* w3, const float* w4, const float* w5,
    u16* __restrict__ out)
{
    int z = blockIdx.z;           // 0..23: tsr = z/4, i = z%4
    int tsr = z >> 2, i = z & 3;
    const float* ws[6] = {w0,w1,w2,w3,w4,w5};
    int ab = (tsr >= 3) ? 1 : 0;
    u16* ob = out + (size_t)((i*2 + ab)*3 + (tsr % 3)) * 65536;
    transpose_body(ws[tsr] + (size_t)i * 65536, ob, 256, 256);
}

// transpose V (cols 512..767 of a 768-wide qkv buffer) -> [z][bh*32+d][784]
__global__ __launch_bounds__(256) void vtrans_kernel(
    const u16* __restrict__ base, int mode,
    u16* __restrict__ outbase)
{
    __shared__ u16 t[64][44];
    int z = blockIdx.z;
    size_t off = (mode ? (size_t)0 : (size_t)(z ^ 1) * 3 * MD) + 512;
    const u16* in = base + off;
    u16* out = outbase + (size_t)z * MD;
    int kt = blockIdx.x, bh = blockIdx.y;
    int bb = bh >> 3, hh = bh & 7;
    int tid = threadIdx.x;
    {
        int r = tid >> 2, c8 = (tid & 3) * 8;
        int krow = kt*64 + r;
        u16x8 u = {0,0,0,0,0,0,0,0};
        if (krow < 784)
            u = *(const u16x8*)(in + (size_t)(bb*784 + krow) * 768 + hh*32 + c8);
        *(u16x8*)&t[r][c8] = u;
    }
    __syncthreads();
    int d = tid >> 3, k8 = (tid & 7) * 8;
    if (kt*64 + k8 + 7 < 784) {
        u16x8 u;
#pragma unroll
        for (int j = 0; j < 8; j++) u[j] = t[k8 + j][d];
        *(u16x8*)&out[(size_t)(bh*32 + d) * 784 + kt*64 + k8] = u;
    }
}

// f[B,256,28,28] fp32 -> s[fi][b*784+hw][d] bf16
__global__ __launch_bounds__(256) void to_seq_kernel(
    const float* f0, const float* f1, const float* f2, const float* f3,
    u16* __restrict__ sbase)
{
    __shared__ float t[16][17];
    int z = blockIdx.z;
    int fi = z & 3, b = z >> 2;
    const float* fs[4] = {f0,f1,f2,f3};
    const float* f = fs[fi] + (size_t)b * 256 * 784;
    u16* s = sbase + (size_t)fi * MD + (size_t)b * 784 * 256;
    int tx = threadIdx.x, ty = threadIdx.y;  // (16,16)
    t[ty][tx] = f[(size_t)(blockIdx.y*16 + ty) * 784 + blockIdx.x*16 + tx];
    __syncthreads();
    s[(size_t)(blockIdx.x*16 + ty) * 256 + blockIdx.y*16 + tx] = f2bf(t[tx][ty]);
}

// y[b*784+hw][d] bf16 -> out[b][d][h][w] fp32
__global__ __launch_bounds__(256) void from_seq_kernel(const u16* __restrict__ y,
                                                       float* __restrict__ out)
{
    __shared__ float t[16][17];
    int b = blockIdx.z;
    const u16* yb = y + (size_t)b * 784 * 256;
    float* ob = out + (size_t)b * 256 * 784;
    int tx = threadIdx.x, ty = threadIdx.y;
    t[ty][tx] = bf2f(yb[(size_t)(blockIdx.x*16 + ty) * 256 + blockIdx.y*16 + tx]);
    __syncthreads();
    ob[(size_t)(blockIdx.y*16 + ty) * 784 + blockIdx.x*16 + tx] = t[tx][ty];
}

// ---------------- host orchestration ----------------------------------------
extern "C" void kernel_launch(void* const* d_in, const int* in_sizes, int n_in,
                              void* d_out, int out_size, void* d_ws, size_t ws_size,
                              hipStream_t stream)
{
    (void)in_sizes; (void)n_in; (void)out_size; (void)ws_size;
    const float* f0 = (const float*)d_in[0];
    const float* f1 = (const float*)d_in[1];
    const float* f2 = (const float*)d_in[2];
    const float* f3 = (const float*)d_in[3];
    const float* Wq_a = (const float*)d_in[4];
    const float* Wk_a = (const float*)d_in[5];
    const float* Wv_a = (const float*)d_in[6];
    const float* Wq_b = (const float*)d_in[7];
    const float* Wk_b = (const float*)d_in[8];
    const float* Wv_b = (const float*)d_in[9];
    const float* bq_a = (const float*)d_in[10];
    const float* bk_a = (const float*)d_in[11];
    const float* bv_a = (const float*)d_in[12];
    const float* bq_b = (const float*)d_in[13];
    const float* bk_b = (const float*)d_in[14];
    const float* bv_b = (const float*)d_in[15];
    const float* gamma = (const float*)d_in[16];
    const float* gamma_ffn = (const float*)d_in[17];
    const float* Wfuse = (const float*)d_in[18];
    const float* bfuse = (const float*)d_in[19];
    const float* W1 = (const float*)d_in[20];
    const float* b1 = (const float*)d_in[21];
    const float* W2 = (const float*)d_in[22];
    const float* b2 = (const float*)d_in[23];
    const float* ln1_g = (const float*)d_in[24];
    const float* ln1_b = (const float*)d_in[25];
    const float* ln2_g = (const float*)d_in[26];
    const float* ln2_b = (const float*)d_in[27];
    const float* fp_ln_g = (const float*)d_in[28];
    const float* fp_ln_b = (const float*)d_in[29];
    const float* fp_W = (const float*)d_in[30];
    const float* fp_b = (const float*)d_in[31];
    const float* ff_ln_g = (const float*)d_in[32];
    const float* ff_ln_b = (const float*)d_in[33];
    const float* ff_W = (const float*)d_in[34];
    const float* ff_b = (const float*)d_in[35];
    const float* mha_Wqkv = (const float*)d_in[36];
    const float* mha_bqkv = (const float*)d_in[37];
    const float* mha_Wo = (const float*)d_in[38];
    const float* mha_bo = (const float*)d_in[39];
    const float* norm_g = (const float*)d_in[40];
    const float* norm_b = (const float*)d_in[41];

    u16* W = (u16*)d_ws;
    u16* projWt = W;                          // 24*65536 = 1572864
    u16* fuseWt = projWt + 1572864;           // 524288
    u16* W1t    = fuseWt + 524288;            // 1048576
    u16* W2t    = W1t + 1048576;              // 1048576
    u16* fpWt   = W2t + 1048576;              // 65536
    u16* ffWt   = fpWt + 65536;               // 262144
    u16* qkvWt  = ffWt + 262144;              // 196608
    u16* WoWt   = qkvWt + 196608;             // 65536
    float* biasc = (float*)(WoWt + 65536);    // 6144 floats
    u16* act    = (u16*)(biasc + 6144);

    u16* s     = act;               // 4 MD
    u16* e     = act + 4*MD;        // 4 MD
    u16* projc = act + 8*MD;        // 24 MD
    u16* vt    = act + 32*MD;       // 8 MD
    u16* fin   = act + 40*MD;       // 8 MD   (peak: 48 MD)
    // overlays (projc/vt dead at time of use)
    u16* ffh  = projc;              // 16 MD
    u16* fb   = projc + 16*MD;      // 4 MD
    u16* xa1  = projc + 20*MD;      // 4 MD
    u16* ffb  = vt;                 // 4 MD

    // input layout + weight pre-transpose
    to_seq_kernel<<<dim3(49,16,16), dim3(16,16), 0, stream>>>(f0,f1,f2,f3, s);
    transpose_w6<<<dim3(8,8,24), dim3(32,8), 0, stream>>>(Wq_a,Wk_a,Wv_a,Wq_b,Wk_b,Wv_b, projWt);
    pack_bias_kernel<<<24, 256, 0, stream>>>(bq_a,bk_a,bv_a,bq_b,bk_b,bv_b, biasc);
    transpose_w<<<dim3(8,16,4), dim3(32,8), 0, stream>>>(Wfuse, fuseWt, 512, 256);
    transpose_w<<<dim3(32,8,4), dim3(32,8), 0, stream>>>(W1, W1t, 256, 1024);
    transpose_w<<<dim3(8,32,4), dim3(32,8), 0, stream>>>(W2, W2t, 1024, 256);
    transpose_w<<<dim3(8,8,1),  dim3(32,8), 0, stream>>>(fp_W, fpWt, 256, 256);
    transpose_w<<<dim3(8,32,1), dim3(32,8), 0, stream>>>(ff_W, ffWt, 1024, 256);
    transpose_w<<<dim3(24,8,1), dim3(32,8), 0, stream>>>(mha_Wqkv, qkvWt, 256, 768);
    transpose_w<<<dim3(8,8,1),  dim3(32,8), 0, stream>>>(mha_Wo, WoWt, 256, 256);

    // two groups of 4 independent block invocations (a-side = s[inv]):
    // A = {bi0,bi2,bi4,bi6}: i={0,0,2,1}, b={1,0,1,0}, accum=0
    // B = {bi1,bi3,bi5,bi7}: i={1,2,3,3}, b={3,2,3,2}, accum=1
    const int GI[2][4] = {{0,0,2,1},{1,2,3,3}};
    const int GB[2][4] = {{1,0,1,0},{3,2,3,2}};

    for (int g = 0; g < 2; g++) {
        int i0 = GI[g][0], i1 = GI[g][1], i2 = GI[g][2], i3 = GI[g][3];
        proj8_kernel<<<dim3(49,12,8), 256, 0, stream>>>(s,
            GB[g][0], GB[g][1], GB[g][2], GB[g][3], i0, i1, i2, i3,
            projWt, biasc, projc);
        vtrans_kernel<<<dim3(13,32,8), 256, 0, stream>>>(projc, 0, vt);
        attn_pair_kernel<<<1792, 256, 0, stream>>>(projc, vt, fin);
        gemm2_kernel<<<dim3(49,4,4), 256, 0, stream>>>(fin, 512, (int)(2*MD),
            fuseWt, 512, i0, i1, i2, i3, 131072, bfuse, 256, fb, 256, (int)MD, 0);
        ln_kernel<<<dim3(784,4), 256, 0, stream>>>(fb, (int)MD,
            s, (int)MD, gamma, i0, i1, i2, i3, ln1_g, ln1_b, 256,
            xa1, (int)MD, 1.0f, 0, 256);
        gemm2_kernel<<<dim3(49,16,4), 256, 0, stream>>>(xa1, 256, (int)MD,
            W1t, 256, i0, i1, i2, i3, 262144, b1, 1024, ffh, 1024, (int)(4*MD), 1);
        gemm2_kernel<<<dim3(49,4,4), 256, 0, stream>>>(ffh, 1024, (int)(4*MD),
            W2t, 1024, i0, i1, i2, i3, 262144, b2, 256, ffb, 256, (int)MD, 0);
        ln_kernel<<<dim3(784,4), 256, 0, stream>>>(ffb, (int)MD,
            xa1, (int)MD, gamma_ffn, i0, i1, i2, i3, ln2_g, ln2_b, 256,
            e, (int)MD, 0.5f, g, 256);
    }

    // final fuse stage (reuse dead scratch; e live until first LN done)
    u16* ln4    = act + 8*MD;        // 4 MD
    u16* allf   = act + 12*MD;       // 4 MD  [3136][1024]
    u16* ffln   = act + 16*MD;       // 4 MD
    u16* x2     = act + 20*MD;       // 1 MD
    u16* qkv    = act + 21*MD;       // 3 MD  [3136][768]
    u16* vtmha  = act + 24*MD;       // 1 MD
    u16* attn_o = act + 25*MD;       // 1 MD
    u16* ymid   = act + 26*MD;       // 1 MD
    u16* yfin   = act + 27*MD;       // 1 MD

    ln_kernel<<<dim3(784,4), 256, 0, stream>>>(e, (int)MD,
        (const u16*)nullptr, 0, (const float*)nullptr, 0,0,0,0,
        fp_ln_g, fp_ln_b, 0, ln4, (int)MD, 1.0f, 0, 256);
    gemm2_kernel<<<dim3(49,4,4), 256, 0, stream>>>(ln4, 256, (int)MD,
        fpWt, 256, 0,0,0,0, 0, fp_b, 0, allf, 1024, 256, 1);
    ln_kernel<<<dim3(784,1), 256, 0, stream>>>(allf, 0,
        (const u16*)nullptr, 0, (const float*)nullptr, 0,0,0,0,
        ff_ln_g, ff_ln_b, 0, ffln, 0, 1.0f, 0, 1024);
    gemm2_kernel<<<dim3(49,4,1), 256, 0, stream>>>(ffln, 1024, 0,
        ffWt, 1024, 0,0,0,0, 0, ff_b, 0, x2, 256, 0, 1);
    gemm2_kernel<<<dim3(49,12,1), 256, 0, stream>>>(x2, 256, 0,
        qkvWt, 256, 0,0,0,0, 0, mha_bqkv, 0, qkv, 768, 0, 0);
    vtrans_kernel<<<dim3(13,32,1), 256, 0, stream>>>(qkv, 1, vtmha);
    attn_mha_kernel<<<224, 256, 0, stream>>>(qkv, vtmha, attn_o);
    gemm2_kernel<<<dim3(49,4,1), 256, 0, stream>>>(attn_o, 256, 0,
        WoWt, 256, 0,0,0,0, 0, mha_bo, 0, ymid, 256, 0, 0);
    ln_kernel<<<dim3(784,1), 256, 0, stream>>>(ymid, 0,
        (const u16*)nullptr, 0, (const float*)nullptr, 0,0,0,0,
        norm_g, norm_b, 0, yfin, 0, 1.0f, 0, 256);
    from_seq_kernel<<<dim3(49,16,4), dim3(16,16), 0, stream>>>(yfin, (float*)d_out);
}